// Round 5
// baseline (485.498 us; speedup 1.0000x reference)
//
#include <hip/hip_runtime.h>
#include <cstdint>
#include <cstddef>

typedef unsigned short u16;
typedef __attribute__((ext_vector_type(8))) short bf16x8;    // 8 bf16 = 4 VGPRs
typedef __attribute__((ext_vector_type(4))) float f32x4;     // 16x16 C/D
typedef __attribute__((ext_vector_type(16))) float f32x16;   // 32x32 C/D

// ---------- helpers ----------
__device__ __forceinline__ u16 f2b(float f) {
    union { float f; unsigned u; } un; un.f = f;
    unsigned r = un.u + 0x7fffu + ((un.u >> 16) & 1u);   // RNE
    return (u16)(r >> 16);
}
__device__ __forceinline__ float b2f(u16 h) {
    union { unsigned u; float f; } un; un.u = ((unsigned)h) << 16;
    return un.f;
}
__device__ __forceinline__ float fast_exp2(float x) {
#if __has_builtin(__builtin_amdgcn_exp2f)
    return __builtin_amdgcn_exp2f(x);
#else
    return exp2f(x);
#endif
}
__device__ __forceinline__ float fast_rcp(float x) {
#if __has_builtin(__builtin_amdgcn_rcpf)
    return __builtin_amdgcn_rcpf(x);
#else
    return 1.f / x;
#endif
}
// tanh-form GELU via exp2: v * s/(s+1), s = 2^(v*(a + b v^2)).
__device__ __forceinline__ float gelu_fast(float v) {
    const float s = fast_exp2(v * (2.30220842f + 0.10294324f * (v * v)));
    return v - v * fast_rcp(s + 1.f);      // s=inf -> rcp->0 -> v (no NaN)
}

// async global->LDS DMA, 16B per lane (wave-uniform base + lane*16 semantics).
__device__ __forceinline__ void stage16(const u16* g, u16* l) {
    __builtin_amdgcn_global_load_lds(
        (const __attribute__((address_space(1))) void*)g,
        (__attribute__((address_space(3))) void*)l, 16, 0, 0);
}

// ---------- fused prologue: x cast + 4 weight transposes ----------
__global__ __launch_bounds__(256)
void prep(const float* __restrict__ x, u16* __restrict__ xb,
          const float* __restrict__ wqkv, u16* __restrict__ wqkvT,
          const float* __restrict__ wout, u16* __restrict__ woutT,
          const float* __restrict__ wff1, u16* __restrict__ wff1T,
          const float* __restrict__ wff2, u16* __restrict__ wff2T) {
    __shared__ float t[32][33];
    const int tid = threadIdx.x;
    int bid = blockIdx.x;
    if (bid < 6144) {
        const int i = bid * 256 + tid;
        float4 v = ((const float4*)x)[i];
        ushort4 o;
        o.x = f2b(v.x); o.y = f2b(v.y); o.z = f2b(v.z); o.w = f2b(v.w);
        ((ushort4*)xb)[i] = o;
        return;
    }
    int tt = bid - 6144;
    const float* in; u16* out; int K, N, bx, by;
    if (tt < 1728)      { in = wqkv; out = wqkvT; K = 768;  N = 2304; bx = tt % 72; by = tt / 72; }
    else if ((tt -= 1728) < 576)  { in = wout; out = woutT; K = 768;  N = 768;  bx = tt % 24; by = tt / 24; }
    else if ((tt -= 576) < 2304)  { in = wff1; out = wff1T; K = 768;  N = 3072; bx = tt % 96; by = tt / 96; }
    else { tt -= 2304;    in = wff2; out = wff2T; K = 3072; N = 768;  bx = tt % 24; by = tt / 24; }
    const int n0 = bx * 32, k0 = by * 32;
    const int tx = tid & 31, ty = tid >> 5;     // 32 x 8
#pragma unroll
    for (int i = 0; i < 4; ++i)
        t[ty + i * 8][tx] = in[(size_t)(k0 + ty + i * 8) * N + n0 + tx];
    __syncthreads();
#pragma unroll
    for (int i = 0; i < 4; ++i)
        out[(size_t)(n0 + ty + i * 8) * K + k0 + tx] = f2b(t[tx][ty + i * 8]);
}

// ---------- GEMM 128 x (NTW*64), 32x32x16 MFMA ----------
// EPI 2: bf16 out = gelu(acc + bias)
// EPI 3: qkv: cols<768 -> q * softmax-scale; 768..1535 -> k; >=1536 -> vt transposed
template <int EPI, int NTW>
__global__ __launch_bounds__(256, 3)
void gemm_bf16(const u16* __restrict__ A, const u16* __restrict__ BT,
               const float* __restrict__ bias,
               void* __restrict__ outp, u16* __restrict__ vt, int M, int N, int K) {
    __shared__ __align__(16) u16 Ash[128 * 64];
    __shared__ __align__(16) u16 Bsh[NTW * 64 * 64];
    const int m0 = blockIdx.y * 128, n0 = blockIdx.x * (NTW * 64);
    const int tid = threadIdx.x;
    const int w = tid >> 6, lane = tid & 63;
    const int l32 = lane & 31, half = lane >> 5;
    const int wm = (w >> 1) * 64, wn = (w & 1) * (NTW * 32);

    const int srow = lane >> 3;
    const int sgrp = (lane & 7) ^ (srow & 7);
    const int xr = l32 & 7;                       // read-side swizzle key (= row&7)

    f32x16 acc[2][NTW];
#pragma unroll
    for (int i = 0; i < 2; ++i)
#pragma unroll
        for (int j = 0; j < NTW; ++j)
#pragma unroll
            for (int e = 0; e < 16; ++e) acc[i][j][e] = 0.f;

    for (int k0 = 0; k0 < K; k0 += 64) {
#pragma unroll
        for (int it = 0; it < 4; ++it) {
            const int c = it * 4 + w;
            const int r = c * 8 + srow;
            stage16(A + (size_t)(m0 + r) * K + k0 + sgrp * 8, &Ash[c * 512 + lane * 8]);
        }
#pragma unroll
        for (int it = 0; it < 2 * NTW; ++it) {
            const int c = it * 4 + w;
            const int r = c * 8 + srow;
            stage16(BT + (size_t)(n0 + r) * K + k0 + sgrp * 8, &Bsh[c * 512 + lane * 8]);
        }
        __syncthreads();

        if constexpr (NTW == 2) {
            bf16x8 af[2][4], bfr[2][4];
#pragma unroll
            for (int mt = 0; mt < 2; ++mt)
#pragma unroll
                for (int kc = 0; kc < 4; ++kc)
                    af[mt][kc] = *(const bf16x8*)&Ash[(wm + mt * 32 + l32) * 64 +
                                                      (((kc << 1) + half) ^ xr) * 8];
#pragma unroll
            for (int nt = 0; nt < 2; ++nt)
#pragma unroll
                for (int kc = 0; kc < 4; ++kc)
                    bfr[nt][kc] = *(const bf16x8*)&Bsh[(wn + nt * 32 + l32) * 64 +
                                                       (((kc << 1) + half) ^ xr) * 8];
#pragma unroll
            for (int mt = 0; mt < 2; ++mt)
#pragma unroll
                for (int nt = 0; nt < 2; ++nt)
#pragma unroll
                    for (int kc = 0; kc < 4; ++kc)
                        acc[mt][nt] = __builtin_amdgcn_mfma_f32_32x32x16_bf16(
                            af[mt][kc], bfr[nt][kc], acc[mt][nt], 0, 0, 0);
        } else {
#pragma unroll
            for (int kc = 0; kc < 4; ++kc) {
                const int ko = (((kc << 1) + half) ^ xr) * 8;
                bf16x8 a0 = *(const bf16x8*)&Ash[(wm + l32) * 64 + ko];
                bf16x8 a1 = *(const bf16x8*)&Ash[(wm + 32 + l32) * 64 + ko];
#pragma unroll
                for (int nt = 0; nt < NTW; ++nt) {
                    bf16x8 bv = *(const bf16x8*)&Bsh[(wn + nt * 32 + l32) * 64 + ko];
                    acc[0][nt] = __builtin_amdgcn_mfma_f32_32x32x16_bf16(
                        a0, bv, acc[0][nt], 0, 0, 0);
                    acc[1][nt] = __builtin_amdgcn_mfma_f32_32x32x16_bf16(
                        a1, bv, acc[1][nt], 0, 0, 0);
                }
            }
        }
        __syncthreads();
    }

    if (EPI == 3 && n0 >= 1536) {
#pragma unroll
        for (int mt = 0; mt < 2; ++mt) {
#pragma unroll
            for (int nt = 0; nt < NTW; ++nt) {
                const int col = n0 + wn + nt * 32 + l32;
                const int c = col - 1536;
                const int h = c >> 6, d = c & 63;
                const float bv = bias[col];
#pragma unroll
                for (int rq = 0; rq < 4; ++rq) {
                    const int row0 = m0 + wm + mt * 32 + rq * 8 + half * 4;
                    const int b = row0 >> 11, tok = row0 & 2047;
                    ushort4 o;
                    o.x = f2b(acc[mt][nt][rq * 4 + 0] + bv);
                    o.y = f2b(acc[mt][nt][rq * 4 + 1] + bv);
                    o.z = f2b(acc[mt][nt][rq * 4 + 2] + bv);
                    o.w = f2b(acc[mt][nt][rq * 4 + 3] + bv);
                    *(ushort4*)&vt[(size_t)(((b * 12 + h) << 6) + d) * 2048 + tok] = o;
                }
            }
        }
        return;
    }

#pragma unroll
    for (int mt = 0; mt < 2; ++mt) {
#pragma unroll
        for (int nt = 0; nt < NTW; ++nt) {
            const int col = n0 + wn + nt * 32 + l32;
            const float bv = bias[col];
#pragma unroll
            for (int reg = 0; reg < 16; ++reg) {
                const int row = m0 + wm + mt * 32 + (reg & 3) + 8 * (reg >> 2) + 4 * half;
                float v = acc[mt][nt][reg] + bv;
                if (EPI == 2)
                    v = gelu_fast(v);
                if (EPI == 3 && col < 768)
                    v *= 0.18033688011112042f;   // fold log2(e)/8 into q
                ((u16*)outp)[(size_t)row * N + col] = f2b(v);
            }
        }
    }
}

// ---------- GEMM 64x128 (32x32x16), bf16 out = acc + bias + resid ----------
template <bool RESF32>
__global__ __launch_bounds__(256, 4)
void gemm_bf16_r64(const u16* __restrict__ A, const u16* __restrict__ BT,
                   const float* __restrict__ bias, const void* __restrict__ resid,
                   u16* __restrict__ outp, int M, int N, int K) {
    __shared__ __align__(16) u16 Ash[64 * 64];
    __shared__ __align__(16) u16 Bsh[128 * 64];
    const int m0 = blockIdx.y * 64, n0 = blockIdx.x * 128;
    const int tid = threadIdx.x;
    const int w = tid >> 6, lane = tid & 63;
    const int l32 = lane & 31, half = lane >> 5;
    const int wm = (w >> 1) * 32, wn = (w & 1) * 64;

    const int srow = lane >> 3;
    const int sgrp = (lane & 7) ^ (srow & 7);
    const int xr = l32 & 7;

    f32x16 acc[2];
#pragma unroll
    for (int j = 0; j < 2; ++j)
#pragma unroll
        for (int e = 0; e < 16; ++e) acc[j][e] = 0.f;

    for (int k0 = 0; k0 < K; k0 += 64) {
#pragma unroll
        for (int it = 0; it < 2; ++it) {
            const int c = it * 4 + w;
            const int r = c * 8 + srow;
            stage16(A + (size_t)(m0 + r) * K + k0 + sgrp * 8, &Ash[c * 512 + lane * 8]);
        }
#pragma unroll
        for (int it = 0; it < 4; ++it) {
            const int c = it * 4 + w;
            const int r = c * 8 + srow;
            stage16(BT + (size_t)(n0 + r) * K + k0 + sgrp * 8, &Bsh[c * 512 + lane * 8]);
        }
        __syncthreads();

        bf16x8 af[4], bfr[2][4];
#pragma unroll
        for (int kc = 0; kc < 4; ++kc)
            af[kc] = *(const bf16x8*)&Ash[(wm + l32) * 64 + (((kc << 1) + half) ^ xr) * 8];
#pragma unroll
        for (int nt = 0; nt < 2; ++nt)
#pragma unroll
            for (int kc = 0; kc < 4; ++kc)
                bfr[nt][kc] = *(const bf16x8*)&Bsh[(wn + nt * 32 + l32) * 64 +
                                                   (((kc << 1) + half) ^ xr) * 8];
#pragma unroll
        for (int nt = 0; nt < 2; ++nt)
#pragma unroll
            for (int kc = 0; kc < 4; ++kc)
                acc[nt] = __builtin_amdgcn_mfma_f32_32x32x16_bf16(
                    af[kc], bfr[nt][kc], acc[nt], 0, 0, 0);
        __syncthreads();
    }

#pragma unroll
    for (int nt = 0; nt < 2; ++nt) {
        const int col = n0 + wn + nt * 32 + l32;
        const float bv = bias[col];
#pragma unroll
        for (int reg = 0; reg < 16; ++reg) {
            const int row = m0 + wm + (reg & 3) + 8 * (reg >> 2) + 4 * half;
            const size_t idx = (size_t)row * N + col;
            const float rv = RESF32 ? ((const float*)resid)[idx]
                                    : b2f(((const u16*)resid)[idx]);
            outp[idx] = f2b(acc[nt][reg] + bv + rv);
        }
    }
}

// ---------- fused flash attention v4: no LDS, no barriers ----------
// K/V fragments loaded per-lane straight from L1/L2 (panels are XCD-L2-resident
// thanks to the block swizzle). Swapped QK^T (mfma(K,Q)) keeps P in registers;
// cvt_pk + permlane32_swap packs P into the PV A-operand. Waves fully independent.
// Q is pre-scaled by log2(e)/8 in the QKV-GEMM epilogue.
__global__ __launch_bounds__(256, 3)
void attn_fused(const u16* __restrict__ qkv, const u16* __restrict__ vt,
                u16* __restrict__ ctx) {
    // bijective XCD swizzle: all 16 q-tiles of one (b,h) on one XCD's L2
    const int orig = blockIdx.x;                  // 0..767
    const int swz = (orig & 7) * 96 + (orig >> 3);
    const int q0 = (swz & 15) * 128;
    const int bh = swz >> 4;                      // 0..47
    const int h = bh % 12, b = bh / 12;

    const int tid = threadIdx.x;
    const int w = tid >> 6, lane = tid & 63;
    const int l32 = lane & 31, hi5 = lane >> 5;

    const u16* Qp = qkv + (size_t)b * 2048 * 2304 + h * 64;
    const u16* Kp = Qp + 768;
    const u16* Vtp = vt + ((size_t)(b * 12 + h) << 6) * 2048;

    // Q as B-operand (32x32x16): lane holds col q=l32, k-elems d = ks*16+hi5*8..+7
    bf16x8 qf[4];
#pragma unroll
    for (int ks = 0; ks < 4; ++ks)
        qf[ks] = *(const bf16x8*)(Qp +
            (size_t)(q0 + w * 32 + l32) * 2304 + ks * 16 + hi5 * 8);

    f32x16 oacc[2];
#pragma unroll
    for (int dt = 0; dt < 2; ++dt)
#pragma unroll
        for (int e = 0; e < 16; ++e) oacc[dt][e] = 0.f;
    float ls0 = 0.f, ls1 = 0.f, ls2 = 0.f, ls3 = 0.f;

    // per-lane base pointers (loop adds small constant offsets)
    const u16* Krow = Kp + (size_t)l32 * 2304 + hi5 * 8;   // + (kt+nt*32)*2304 + ks*16
    const u16* Vrow = Vtp + (size_t)l32 * 2048 + hi5 * 8;  // + dt*32*2048 + kt+nt*32+kh*16

    for (int kt = 0; kt < 2048; kt += 64) {
#pragma unroll
        for (int nt = 0; nt < 2; ++nt) {
            // ---- K fragments straight from global (L1/L2) ----
            const u16* kbase = Krow + (size_t)(kt + nt * 32) * 2304;
            bf16x8 kfr[4];
#pragma unroll
            for (int ks = 0; ks < 4; ++ks)
                kfr[ks] = *(const bf16x8*)(kbase + ks * 16);

            // ---- QK^T (swapped): S[tok][q], tokens in regs, q on lanes ----
            f32x16 sacc;
#pragma unroll
            for (int e = 0; e < 16; ++e) sacc[e] = 0.f;
#pragma unroll
            for (int ks = 0; ks < 4; ++ks)
                sacc = __builtin_amdgcn_mfma_f32_32x32x16_bf16(
                    kfr[ks], qf[ks], sacc, 0, 0, 0);

            // ---- softmax (max-free, Q pre-scaled): exp2 + lane-local sums ----
#pragma unroll
            for (int e = 0; e < 16; ++e) sacc[e] = fast_exp2(sacc[e]);
            ls0 += (sacc[0] + sacc[1]) + (sacc[8] + sacc[9]);
            ls1 += (sacc[2] + sacc[3]) + (sacc[10] + sacc[11]);
            ls2 += (sacc[4] + sacc[5]) + (sacc[12] + sacc[13]);
            ls3 += (sacc[6] + sacc[7]) + (sacc[14] + sacc[15]);

            // ---- pack P (cvt_pk + permlane32_swap) and PV accumulate ----
#pragma unroll
            for (int kh = 0; kh < 2; ++kh) {
                const int rb = kh * 8;
                unsigned c01, c23, c45, c67;
                asm("v_cvt_pk_bf16_f32 %0, %1, %2"
                    : "=v"(c01) : "v"(sacc[rb + 0]), "v"(sacc[rb + 1]));
                asm("v_cvt_pk_bf16_f32 %0, %1, %2"
                    : "=v"(c23) : "v"(sacc[rb + 2]), "v"(sacc[rb + 3]));
                asm("v_cvt_pk_bf16_f32 %0, %1, %2"
                    : "=v"(c45) : "v"(sacc[rb + 4]), "v"(sacc[rb + 5]));
                asm("v_cvt_pk_bf16_f32 %0, %1, %2"
                    : "=v"(c67) : "v"(sacc[rb + 6]), "v"(sacc[rb + 7]));
                asm("v_permlane32_swap_b32 %0, %1" : "+v"(c01), "+v"(c45));
                asm("v_permlane32_swap_b32 %0, %1" : "+v"(c23), "+v"(c67));
                union { unsigned u[4]; bf16x8 v; } pf;
                pf.u[0] = c01; pf.u[1] = c23; pf.u[2] = c45; pf.u[3] = c67;
#pragma unroll
                for (int dt = 0; dt < 2; ++dt) {
                    bf16x8 vfr = *(const bf16x8*)(Vrow +
                        (size_t)dt * 32 * 2048 + kt + nt * 32 + kh * 16);
                    oacc[dt] = __builtin_amdgcn_mfma_f32_32x32x16_bf16(
                        pf.v, vfr, oacc[dt], 0, 0, 0);
                }
            }
        }
    }

    // row sum: lane q=l32 holds half the tokens; partner (lane^32) has the rest
    float lsum = (ls0 + ls1) + (ls2 + ls3);
    lsum += __shfl_xor(lsum, 32);
    const float linv = 1.f / lsum;

    // per-output-row scale: row q_r's sum lives on lane q_r
    float scv[16];
#pragma unroll
    for (int reg = 0; reg < 16; ++reg) {
        const int q_r = (reg & 3) + 8 * (reg >> 2) + 4 * hi5;
        scv[reg] = __shfl(linv, q_r);
    }

#pragma unroll
    for (int dt = 0; dt < 2; ++dt)
#pragma unroll
        for (int reg = 0; reg < 16; ++reg) {
            const int q_r = (reg & 3) + 8 * (reg >> 2) + 4 * hi5;
            const int row = q0 + w * 32 + q_r;
            ctx[(size_t)(b * 2048 + row) * 768 + h * 64 + dt * 32 + l32] =
                f2b(oacc[dt][reg] * scv[reg]);
        }
}

// ---------- LayerNorm over H=768 (bf16 in); OUTF32 ? f32 out : bf16 out ----------
template <bool OUTF32>
__global__ __launch_bounds__(256)
void layernorm_k(const u16* __restrict__ y, const float* __restrict__ g,
                 const float* __restrict__ be, float* __restrict__ outf,
                 u16* __restrict__ outb) {
    const int row = blockIdx.x;
    const int tid = threadIdx.x;
    const u16* yr = y + (size_t)row * 768;
    float v[3], s = 0.f, s2 = 0.f;
#pragma unroll
    for (int i = 0; i < 3; ++i) {
        float x = b2f(yr[tid + i * 256]);
        v[i] = x; s += x; s2 += x * x;
    }
#pragma unroll
    for (int off = 32; off >= 1; off >>= 1) {
        s += __shfl_xor(s, off);
        s2 += __shfl_xor(s2, off);
    }
    __shared__ float red[2][4];
    const int w = tid >> 6;
    if ((tid & 63) == 0) { red[0][w] = s; red[1][w] = s2; }
    __syncthreads();
    s = red[0][0] + red[0][1] + red[0][2] + red[0][3];
    s2 = red[1][0] + red[1][1] + red[1][2] + red[1][3];
    const float mu = s * (1.f / 768.f);
    const float var = s2 * (1.f / 768.f) - mu * mu;
    const float rs = rsqrtf(var + 1e-12f);
#pragma unroll
    for (int i = 0; i < 3; ++i) {
        const int c = tid + i * 256;
        const float o = (v[i] - mu) * rs * g[c] + be[c];
        if (OUTF32) outf[(size_t)row * 768 + c] = o;
        else        outb[(size_t)row * 768 + c] = f2b(o);
    }
}

// ---------- orchestration ----------
extern "C" void kernel_launch(void* const* d_in, const int* in_sizes, int n_in,
                              void* d_out, int out_size, void* d_ws, size_t ws_size,
                              hipStream_t stream) {
    const float* x    = (const float*)d_in[0];
    const float* wqkv = (const float*)d_in[1];
    const float* bqkv = (const float*)d_in[2];
    const float* wout = (const float*)d_in[3];
    const float* bout = (const float*)d_in[4];
    const float* wff1 = (const float*)d_in[5];
    const float* bff1 = (const float*)d_in[6];
    const float* wff2 = (const float*)d_in[7];
    const float* bff2 = (const float*)d_in[8];
    const float* g1   = (const float*)d_in[9];
    const float* be1  = (const float*)d_in[10];
    const float* g2   = (const float*)d_in[11];
    const float* be2  = (const float*)d_in[12];

    char* ws = (char*)d_ws;
    constexpr size_t o_xb    = 0;
    constexpr size_t o_wqkvT = o_xb    + (size_t)8192 * 768 * 2;
    constexpr size_t o_woutT = o_wqkvT + (size_t)2304 * 768 * 2;
    constexpr size_t o_wff1T = o_woutT + (size_t)768 * 768 * 2;
    constexpr size_t o_wff2T = o_wff1T + (size_t)3072 * 768 * 2;
    constexpr size_t o_qkv   = o_wff2T + (size_t)768 * 3072 * 2;
    constexpr size_t o_ctx   = o_qkv   + (size_t)8192 * 2304 * 2;
    constexpr size_t o_y     = o_ctx   + (size_t)8192 * 768 * 2;
    constexpr size_t o_x1b   = o_y     + (size_t)8192 * 768 * 2;
    constexpr size_t o_vt    = o_x1b;   // vt dead before x1b is written
    constexpr size_t o_h     = o_qkv;   // hb reuses qkv+ctx region

    u16*   xb    = (u16*)(ws + o_xb);
    u16*   wqkvT = (u16*)(ws + o_wqkvT);
    u16*   woutT = (u16*)(ws + o_woutT);
    u16*   wff1T = (u16*)(ws + o_wff1T);
    u16*   wff2T = (u16*)(ws + o_wff2T);
    u16*   qkvb  = (u16*)(ws + o_qkv);
    u16*   ctxb  = (u16*)(ws + o_ctx);
    u16*   yb    = (u16*)(ws + o_y);
    u16*   x1b   = (u16*)(ws + o_x1b);
    u16*   hb    = (u16*)(ws + o_h);
    u16*   vt    = (u16*)(ws + o_vt);

    // fused prologue: x cast + 4 weight transposes
    prep<<<13056, 256, 0, stream>>>(x, xb, wqkv, wqkvT, wout, woutT,
                                    wff1, wff1T, wff2, wff2T);

    // qkv = x @ w_qkv + b ; q (pre-scaled), k -> qkvb bf16, v -> vt transposed
    gemm_bf16<3, 3><<<dim3(2304 / 192, 8192 / 128), 256, 0, stream>>>(
        xb, wqkvT, bqkv, qkvb, vt, 8192, 2304, 768);

    // fused attention -> ctx bf16 [8192, 768]; 768 blocks, XCD-swizzled in-kernel
    attn_fused<<<768, 256, 0, stream>>>(qkvb, vt, ctxb);

    // y = ctx @ w_out + b_out + x  -> bf16
    gemm_bf16_r64<true><<<dim3(768 / 128, 8192 / 64), 256, 0, stream>>>(
        ctxb, woutT, bout, x, yb, 8192, 768, 768);

    // x1 = LN(y) -> bf16 (vt dead after attention)
    layernorm_k<false><<<8192, 256, 0, stream>>>(yb, g1, be1, nullptr, x1b);

    // h = gelu(x1 @ w_ff1 + b_ff1) -> bf16 [8192, 3072]
    gemm_bf16<2, 2><<<dim3(3072 / 128, 8192 / 128), 256, 0, stream>>>(
        x1b, wff1T, bff1, hb, nullptr, 8192, 3072, 768);

    // y2 = h @ w_ff2 + b_ff2 + x1 -> bf16 (yb dead after LN1)
    gemm_bf16_r64<false><<<dim3(768 / 128, 8192 / 64), 256, 0, stream>>>(
        hb, wff2T, bff2, x1b, yb, 8192, 768, 3072);

    // out = LN(y2) -> f32
    layernorm_k<true><<<8192, 256, 0, stream>>>(yb, g2, be2, (float*)d_out, nullptr);
}

// Round 6
// 367.942 us; speedup vs baseline: 1.3195x; 1.3195x over previous
//
#include <hip/hip_runtime.h>
#include <cstdint>
#include <cstddef>

typedef unsigned short u16;
typedef __attribute__((ext_vector_type(8))) short bf16x8;    // 8 bf16 = 4 VGPRs
typedef __attribute__((ext_vector_type(4))) float f32x4;     // 16x16 C/D
typedef __attribute__((ext_vector_type(16))) float f32x16;   // 32x32 C/D

// ---------- helpers ----------
__device__ __forceinline__ u16 f2b(float f) {
    union { float f; unsigned u; } un; un.f = f;
    unsigned r = un.u + 0x7fffu + ((un.u >> 16) & 1u);   // RNE
    return (u16)(r >> 16);
}
__device__ __forceinline__ float b2f(u16 h) {
    union { unsigned u; float f; } un; un.u = ((unsigned)h) << 16;
    return un.f;
}
__device__ __forceinline__ float fast_exp2(float x) {
#if __has_builtin(__builtin_amdgcn_exp2f)
    return __builtin_amdgcn_exp2f(x);
#else
    return exp2f(x);
#endif
}
__device__ __forceinline__ float fast_rcp(float x) {
#if __has_builtin(__builtin_amdgcn_rcpf)
    return __builtin_amdgcn_rcpf(x);
#else
    return 1.f / x;
#endif
}
// tanh-form GELU via exp2: v * s/(s+1), s = 2^(v*(a + b v^2)).
__device__ __forceinline__ float gelu_fast(float v) {
    const float s = fast_exp2(v * (2.30220842f + 0.10294324f * (v * v)));
    return v - v * fast_rcp(s + 1.f);      // s=inf -> rcp->0 -> v (no NaN)
}

// async global->LDS DMA, 16B per lane (wave-uniform base + lane*16 semantics).
__device__ __forceinline__ void stage16(const u16* g, u16* l) {
    __builtin_amdgcn_global_load_lds(
        (const __attribute__((address_space(1))) void*)g,
        (__attribute__((address_space(3))) void*)l, 16, 0, 0);
}

// ---------- fused prologue: x cast + 4 weight transposes ----------
__global__ __launch_bounds__(256)
void prep(const float* __restrict__ x, u16* __restrict__ xb,
          const float* __restrict__ wqkv, u16* __restrict__ wqkvT,
          const float* __restrict__ wout, u16* __restrict__ woutT,
          const float* __restrict__ wff1, u16* __restrict__ wff1T,
          const float* __restrict__ wff2, u16* __restrict__ wff2T) {
    __shared__ float t[32][33];
    const int tid = threadIdx.x;
    int bid = blockIdx.x;
    if (bid < 6144) {
        const int i = bid * 256 + tid;
        float4 v = ((const float4*)x)[i];
        ushort4 o;
        o.x = f2b(v.x); o.y = f2b(v.y); o.z = f2b(v.z); o.w = f2b(v.w);
        ((ushort4*)xb)[i] = o;
        return;
    }
    int tt = bid - 6144;
    const float* in; u16* out; int K, N, bx, by;
    if (tt < 1728)      { in = wqkv; out = wqkvT; K = 768;  N = 2304; bx = tt % 72; by = tt / 72; }
    else if ((tt -= 1728) < 576)  { in = wout; out = woutT; K = 768;  N = 768;  bx = tt % 24; by = tt / 24; }
    else if ((tt -= 576) < 2304)  { in = wff1; out = wff1T; K = 768;  N = 3072; bx = tt % 96; by = tt / 96; }
    else { tt -= 2304;    in = wff2; out = wff2T; K = 3072; N = 768;  bx = tt % 24; by = tt / 24; }
    const int n0 = bx * 32, k0 = by * 32;
    const int tx = tid & 31, ty = tid >> 5;     // 32 x 8
#pragma unroll
    for (int i = 0; i < 4; ++i)
        t[ty + i * 8][tx] = in[(size_t)(k0 + ty + i * 8) * N + n0 + tx];
    __syncthreads();
#pragma unroll
    for (int i = 0; i < 4; ++i)
        out[(size_t)(n0 + ty + i * 8) * K + k0 + tx] = f2b(t[tx][ty + i * 8]);
}

// ---------- GEMM 128 x (NTW*64), 32x32x16 MFMA ----------
// EPI 2: bf16 out = gelu(acc + bias)
// EPI 3: qkv: cols<768 -> q * softmax-scale; 768..1535 -> k; >=1536 -> vt transposed
template <int EPI, int NTW>
__global__ __launch_bounds__(256, 3)
void gemm_bf16(const u16* __restrict__ A, const u16* __restrict__ BT,
               const float* __restrict__ bias,
               void* __restrict__ outp, u16* __restrict__ vt, int M, int N, int K) {
    __shared__ __align__(16) u16 Ash[128 * 64];
    __shared__ __align__(16) u16 Bsh[NTW * 64 * 64];
    const int m0 = blockIdx.y * 128, n0 = blockIdx.x * (NTW * 64);
    const int tid = threadIdx.x;
    const int w = tid >> 6, lane = tid & 63;
    const int l32 = lane & 31, half = lane >> 5;
    const int wm = (w >> 1) * 64, wn = (w & 1) * (NTW * 32);

    const int srow = lane >> 3;
    const int sgrp = (lane & 7) ^ (srow & 7);
    const int xr = l32 & 7;                       // read-side swizzle key (= row&7)

    f32x16 acc[2][NTW];
#pragma unroll
    for (int i = 0; i < 2; ++i)
#pragma unroll
        for (int j = 0; j < NTW; ++j)
#pragma unroll
            for (int e = 0; e < 16; ++e) acc[i][j][e] = 0.f;

    for (int k0 = 0; k0 < K; k0 += 64) {
#pragma unroll
        for (int it = 0; it < 4; ++it) {
            const int c = it * 4 + w;
            const int r = c * 8 + srow;
            stage16(A + (size_t)(m0 + r) * K + k0 + sgrp * 8, &Ash[c * 512 + lane * 8]);
        }
#pragma unroll
        for (int it = 0; it < 2 * NTW; ++it) {
            const int c = it * 4 + w;
            const int r = c * 8 + srow;
            stage16(BT + (size_t)(n0 + r) * K + k0 + sgrp * 8, &Bsh[c * 512 + lane * 8]);
        }
        __syncthreads();

        if constexpr (NTW == 2) {
            bf16x8 af[2][4], bfr[2][4];
#pragma unroll
            for (int mt = 0; mt < 2; ++mt)
#pragma unroll
                for (int kc = 0; kc < 4; ++kc)
                    af[mt][kc] = *(const bf16x8*)&Ash[(wm + mt * 32 + l32) * 64 +
                                                      (((kc << 1) + half) ^ xr) * 8];
#pragma unroll
            for (int nt = 0; nt < 2; ++nt)
#pragma unroll
                for (int kc = 0; kc < 4; ++kc)
                    bfr[nt][kc] = *(const bf16x8*)&Bsh[(wn + nt * 32 + l32) * 64 +
                                                       (((kc << 1) + half) ^ xr) * 8];
#pragma unroll
            for (int mt = 0; mt < 2; ++mt)
#pragma unroll
                for (int nt = 0; nt < 2; ++nt)
#pragma unroll
                    for (int kc = 0; kc < 4; ++kc)
                        acc[mt][nt] = __builtin_amdgcn_mfma_f32_32x32x16_bf16(
                            af[mt][kc], bfr[nt][kc], acc[mt][nt], 0, 0, 0);
        } else {
#pragma unroll
            for (int kc = 0; kc < 4; ++kc) {
                const int ko = (((kc << 1) + half) ^ xr) * 8;
                bf16x8 a0 = *(const bf16x8*)&Ash[(wm + l32) * 64 + ko];
                bf16x8 a1 = *(const bf16x8*)&Ash[(wm + 32 + l32) * 64 + ko];
#pragma unroll
                for (int nt = 0; nt < NTW; ++nt) {
                    bf16x8 bv = *(const bf16x8*)&Bsh[(wn + nt * 32 + l32) * 64 + ko];
                    acc[0][nt] = __builtin_amdgcn_mfma_f32_32x32x16_bf16(
                        a0, bv, acc[0][nt], 0, 0, 0);
                    acc[1][nt] = __builtin_amdgcn_mfma_f32_32x32x16_bf16(
                        a1, bv, acc[1][nt], 0, 0, 0);
                }
            }
        }
        __syncthreads();
    }

    if (EPI == 3 && n0 >= 1536) {
#pragma unroll
        for (int mt = 0; mt < 2; ++mt) {
#pragma unroll
            for (int nt = 0; nt < NTW; ++nt) {
                const int col = n0 + wn + nt * 32 + l32;
                const int c = col - 1536;
                const int h = c >> 6, d = c & 63;
                const float bv = bias[col];
#pragma unroll
                for (int rq = 0; rq < 4; ++rq) {
                    const int row0 = m0 + wm + mt * 32 + rq * 8 + half * 4;
                    const int b = row0 >> 11, tok = row0 & 2047;
                    ushort4 o;
                    o.x = f2b(acc[mt][nt][rq * 4 + 0] + bv);
                    o.y = f2b(acc[mt][nt][rq * 4 + 1] + bv);
                    o.z = f2b(acc[mt][nt][rq * 4 + 2] + bv);
                    o.w = f2b(acc[mt][nt][rq * 4 + 3] + bv);
                    *(ushort4*)&vt[(size_t)(((b * 12 + h) << 6) + d) * 2048 + tok] = o;
                }
            }
        }
        return;
    }

#pragma unroll
    for (int mt = 0; mt < 2; ++mt) {
#pragma unroll
        for (int nt = 0; nt < NTW; ++nt) {
            const int col = n0 + wn + nt * 32 + l32;
            const float bv = bias[col];
#pragma unroll
            for (int reg = 0; reg < 16; ++reg) {
                const int row = m0 + wm + mt * 32 + (reg & 3) + 8 * (reg >> 2) + 4 * half;
                float v = acc[mt][nt][reg] + bv;
                if (EPI == 2)
                    v = gelu_fast(v);
                if (EPI == 3 && col < 768)
                    v *= 0.18033688011112042f;   // fold log2(e)/8 into q
                ((u16*)outp)[(size_t)row * N + col] = f2b(v);
            }
        }
    }
}

// ---------- GEMM 64x128 (32x32x16), bf16 out = acc + bias + resid ----------
template <bool RESF32>
__global__ __launch_bounds__(256, 4)
void gemm_bf16_r64(const u16* __restrict__ A, const u16* __restrict__ BT,
                   const float* __restrict__ bias, const void* __restrict__ resid,
                   u16* __restrict__ outp, int M, int N, int K) {
    __shared__ __align__(16) u16 Ash[64 * 64];
    __shared__ __align__(16) u16 Bsh[128 * 64];
    const int m0 = blockIdx.y * 64, n0 = blockIdx.x * 128;
    const int tid = threadIdx.x;
    const int w = tid >> 6, lane = tid & 63;
    const int l32 = lane & 31, half = lane >> 5;
    const int wm = (w >> 1) * 32, wn = (w & 1) * 64;

    const int srow = lane >> 3;
    const int sgrp = (lane & 7) ^ (srow & 7);
    const int xr = l32 & 7;

    f32x16 acc[2];
#pragma unroll
    for (int j = 0; j < 2; ++j)
#pragma unroll
        for (int e = 0; e < 16; ++e) acc[j][e] = 0.f;

    for (int k0 = 0; k0 < K; k0 += 64) {
#pragma unroll
        for (int it = 0; it < 2; ++it) {
            const int c = it * 4 + w;
            const int r = c * 8 + srow;
            stage16(A + (size_t)(m0 + r) * K + k0 + sgrp * 8, &Ash[c * 512 + lane * 8]);
        }
#pragma unroll
        for (int it = 0; it < 4; ++it) {
            const int c = it * 4 + w;
            const int r = c * 8 + srow;
            stage16(BT + (size_t)(n0 + r) * K + k0 + sgrp * 8, &Bsh[c * 512 + lane * 8]);
        }
        __syncthreads();

        bf16x8 af[4], bfr[2][4];
#pragma unroll
        for (int kc = 0; kc < 4; ++kc)
            af[kc] = *(const bf16x8*)&Ash[(wm + l32) * 64 + (((kc << 1) + half) ^ xr) * 8];
#pragma unroll
        for (int nt = 0; nt < 2; ++nt)
#pragma unroll
            for (int kc = 0; kc < 4; ++kc)
                bfr[nt][kc] = *(const bf16x8*)&Bsh[(wn + nt * 32 + l32) * 64 +
                                                   (((kc << 1) + half) ^ xr) * 8];
#pragma unroll
        for (int nt = 0; nt < 2; ++nt)
#pragma unroll
            for (int kc = 0; kc < 4; ++kc)
                acc[nt] = __builtin_amdgcn_mfma_f32_32x32x16_bf16(
                    af[kc], bfr[nt][kc], acc[nt], 0, 0, 0);
        __syncthreads();
    }

#pragma unroll
    for (int nt = 0; nt < 2; ++nt) {
        const int col = n0 + wn + nt * 32 + l32;
        const float bv = bias[col];
#pragma unroll
        for (int reg = 0; reg < 16; ++reg) {
            const int row = m0 + wm + (reg & 3) + 8 * (reg >> 2) + 4 * half;
            const size_t idx = (size_t)row * N + col;
            const float rv = RESF32 ? ((const float*)resid)[idx]
                                    : b2f(((const u16*)resid)[idx]);
            outp[idx] = f2b(acc[nt][reg] + bv + rv);
        }
    }
}

// ---------- fused flash attention v6: LDS-staged (round-3 structure) ----------
// 32x32 MFMA, swapped QK^T (mfma(K,Q)) keeps P in registers; cvt_pk +
// permlane32_swap packs P into the PV A-operand. Q pre-scaled by log2(e)/8 in
// the QKV epilogue (no in-loop scale). V fragments read from LDS right after
// the QK MFMAs so their latency hides under the softmax VALU phase.
__global__ __launch_bounds__(256, 3)
void attn_fused(const u16* __restrict__ qkv, const u16* __restrict__ vt,
                u16* __restrict__ ctx) {
    __shared__ __align__(16) u16 Ksh[2][64 * 64];   // [tok][d]
    __shared__ __align__(16) u16 Vsh[2][64 * 64];   // [d][tok]

    // bijective XCD swizzle: all 16 q-tiles of one (b,h) on one XCD's L2
    const int orig = blockIdx.x;                  // 0..767
    const int swz = (orig & 7) * 96 + (orig >> 3);
    const int q0 = (swz & 15) * 128;
    const int bh = swz >> 4;                      // 0..47
    const int h = bh % 12, b = bh / 12;

    const int tid = threadIdx.x;
    const int w = tid >> 6, lane = tid & 63;
    const int l32 = lane & 31, hi5 = lane >> 5;
    const int xr8 = l32 & 7;                      // read-side swizzle key (= row&7)

    const int srow = lane >> 3;
    const int sgrp = (lane & 7) ^ (srow & 7);

    const u16* Qp = qkv + (size_t)b * 2048 * 2304 + h * 64;
    const u16* Kp = Qp + 768;
    const u16* Vtp = vt + ((size_t)(b * 12 + h) << 6) * 2048;

    // Q as B-operand (32x32x16): lane holds col q=l32, k-elems d = ks*16+hi5*8..+7
    bf16x8 qf[4];
#pragma unroll
    for (int ks = 0; ks < 4; ++ks)
        qf[ks] = *(const bf16x8*)(Qp +
            (size_t)(q0 + w * 32 + l32) * 2304 + ks * 16 + hi5 * 8);
    // drain Q loads so manual vmcnt bookkeeping below is exact
    asm volatile("s_waitcnt vmcnt(0)" ::: "memory");
    __builtin_amdgcn_sched_barrier(0);

    f32x16 oacc[2];
#pragma unroll
    for (int dt = 0; dt < 2; ++dt)
#pragma unroll
        for (int e = 0; e < 16; ++e) oacc[dt][e] = 0.f;
    float ls0 = 0.f, ls1 = 0.f, ls2 = 0.f, ls3 = 0.f;

    // 4 stage16 per wave per tile (2 K + 2 V)
    auto stage_kv = [&](int buf, int ktt) {
#pragma unroll
        for (int it = 0; it < 2; ++it) {
            const int c = it * 4 + w;
            const int r = c * 8 + srow;
            stage16(Kp + (size_t)(ktt + r) * 2304 + sgrp * 8,
                    &Ksh[buf][c * 512 + lane * 8]);
        }
#pragma unroll
        for (int it = 0; it < 2; ++it) {
            const int c = it * 4 + w;
            const int r = c * 8 + srow;      // r = d
            stage16(Vtp + (size_t)r * 2048 + ktt + sgrp * 8,
                    &Vsh[buf][c * 512 + lane * 8]);
        }
    };

    stage_kv(0, 0);

    for (int t = 0; t < 32; ++t) {
        const int cur = t & 1;
        if (t < 31) {
            stage_kv(cur ^ 1, (t + 1) * 64);
            asm volatile("s_waitcnt vmcnt(4)" ::: "memory");  // cur tile landed
        } else {
            asm volatile("s_waitcnt vmcnt(0)" ::: "memory");
        }
        __builtin_amdgcn_sched_barrier(0);
        __builtin_amdgcn_s_barrier();

        // ---- K fragments + QK^T (swapped): S[tok][q] ----
        bf16x8 kfr[2][4];
#pragma unroll
        for (int nt = 0; nt < 2; ++nt)
#pragma unroll
            for (int ks = 0; ks < 4; ++ks)
                kfr[nt][ks] = *(const bf16x8*)&Ksh[cur][(nt * 32 + l32) * 64 +
                                                       (((ks << 1) + hi5) ^ xr8) * 8];

        f32x16 sacc[2];
#pragma unroll
        for (int nt = 0; nt < 2; ++nt)
#pragma unroll
            for (int e = 0; e < 16; ++e) sacc[nt][e] = 0.f;

        __builtin_amdgcn_s_setprio(1);
#pragma unroll
        for (int nt = 0; nt < 2; ++nt)
#pragma unroll
            for (int ks = 0; ks < 4; ++ks)
                sacc[nt] = __builtin_amdgcn_mfma_f32_32x32x16_bf16(
                    kfr[nt][ks], qf[ks], sacc[nt], 0, 0, 0);
        __builtin_amdgcn_s_setprio(0);

        // ---- V fragments early: LDS latency hides under softmax VALU ----
        bf16x8 vfr[2][4];   // [dt][s = nt*2+kh]
#pragma unroll
        for (int dt = 0; dt < 2; ++dt)
#pragma unroll
            for (int s = 0; s < 4; ++s)
                vfr[dt][s] = *(const bf16x8*)&Vsh[cur][(dt * 32 + l32) * 64 +
                                                      (((s << 1) + hi5) ^ xr8) * 8];

        // ---- softmax (max-free, Q pre-scaled): exp2 + lane-local sums ----
#pragma unroll
        for (int nt = 0; nt < 2; ++nt) {
#pragma unroll
            for (int e = 0; e < 16; ++e)
                sacc[nt][e] = fast_exp2(sacc[nt][e]);
            ls0 += (sacc[nt][0] + sacc[nt][1]) + (sacc[nt][8] + sacc[nt][9]);
            ls1 += (sacc[nt][2] + sacc[nt][3]) + (sacc[nt][10] + sacc[nt][11]);
            ls2 += (sacc[nt][4] + sacc[nt][5]) + (sacc[nt][12] + sacc[nt][13]);
            ls3 += (sacc[nt][6] + sacc[nt][7]) + (sacc[nt][14] + sacc[nt][15]);
        }

        // ---- pack P (cvt_pk + permlane32_swap) and PV accumulate ----
        __builtin_amdgcn_s_setprio(1);
#pragma unroll
        for (int nt = 0; nt < 2; ++nt) {
#pragma unroll
            for (int kh = 0; kh < 2; ++kh) {      // 16-token k-step
                const int rb = kh * 8;
                unsigned c01, c23, c45, c67;
                asm("v_cvt_pk_bf16_f32 %0, %1, %2"
                    : "=v"(c01) : "v"(sacc[nt][rb + 0]), "v"(sacc[nt][rb + 1]));
                asm("v_cvt_pk_bf16_f32 %0, %1, %2"
                    : "=v"(c23) : "v"(sacc[nt][rb + 2]), "v"(sacc[nt][rb + 3]));
                asm("v_cvt_pk_bf16_f32 %0, %1, %2"
                    : "=v"(c45) : "v"(sacc[nt][rb + 4]), "v"(sacc[nt][rb + 5]));
                asm("v_cvt_pk_bf16_f32 %0, %1, %2"
                    : "=v"(c67) : "v"(sacc[nt][rb + 6]), "v"(sacc[nt][rb + 7]));
                // lane<32 <-> lane>=32 half exchange: fills tokens hi5*8..+7 in order
                asm("v_permlane32_swap_b32 %0, %1" : "+v"(c01), "+v"(c45));
                asm("v_permlane32_swap_b32 %0, %1" : "+v"(c23), "+v"(c67));
                union { unsigned u[4]; bf16x8 v; } pf;
                pf.u[0] = c01; pf.u[1] = c23; pf.u[2] = c45; pf.u[3] = c67;
#pragma unroll
                for (int dt = 0; dt < 2; ++dt)
                    oacc[dt] = __builtin_amdgcn_mfma_f32_32x32x16_bf16(
                        pf.v, vfr[dt][nt * 2 + kh], oacc[dt], 0, 0, 0);
            }
        }
        __builtin_amdgcn_s_setprio(0);
        __builtin_amdgcn_s_barrier();
    }

    // row sum: lane q=l32 holds half the tokens; partner (lane^32) has the rest
    float lsum = (ls0 + ls1) + (ls2 + ls3);
    lsum += __shfl_xor(lsum, 32);
    const float linv = 1.f / lsum;

    // per-output-row scale: row q_r's sum lives on lane q_r
    float scv[16];
#pragma unroll
    for (int reg = 0; reg < 16; ++reg) {
        const int q_r = (reg & 3) + 8 * (reg >> 2) + 4 * hi5;
        scv[reg] = __shfl(linv, q_r);
    }

#pragma unroll
    for (int dt = 0; dt < 2; ++dt)
#pragma unroll
        for (int reg = 0; reg < 16; ++reg) {
            const int q_r = (reg & 3) + 8 * (reg >> 2) + 4 * hi5;
            const int row = q0 + w * 32 + q_r;
            ctx[(size_t)(b * 2048 + row) * 768 + h * 64 + dt * 32 + l32] =
                f2b(oacc[dt][reg] * scv[reg]);
        }
}

// ---------- LayerNorm over H=768 (bf16 in); OUTF32 ? f32 out : bf16 out ----------
template <bool OUTF32>
__global__ __launch_bounds__(256)
void layernorm_k(const u16* __restrict__ y, const float* __restrict__ g,
                 const float* __restrict__ be, float* __restrict__ outf,
                 u16* __restrict__ outb) {
    const int row = blockIdx.x;
    const int tid = threadIdx.x;
    const u16* yr = y + (size_t)row * 768;
    float v[3], s = 0.f, s2 = 0.f;
#pragma unroll
    for (int i = 0; i < 3; ++i) {
        float x = b2f(yr[tid + i * 256]);
        v[i] = x; s += x; s2 += x * x;
    }
#pragma unroll
    for (int off = 32; off >= 1; off >>= 1) {
        s += __shfl_xor(s, off);
        s2 += __shfl_xor(s2, off);
    }
    __shared__ float red[2][4];
    const int w = tid >> 6;
    if ((tid & 63) == 0) { red[0][w] = s; red[1][w] = s2; }
    __syncthreads();
    s = red[0][0] + red[0][1] + red[0][2] + red[0][3];
    s2 = red[1][0] + red[1][1] + red[1][2] + red[1][3];
    const float mu = s * (1.f / 768.f);
    const float var = s2 * (1.f / 768.f) - mu * mu;
    const float rs = rsqrtf(var + 1e-12f);
#pragma unroll
    for (int i = 0; i < 3; ++i) {
        const int c = tid + i * 256;
        const float o = (v[i] - mu) * rs * g[c] + be[c];
        if (OUTF32) outf[(size_t)row * 768 + c] = o;
        else        outb[(size_t)row * 768 + c] = f2b(o);
    }
}

// ---------- orchestration ----------
extern "C" void kernel_launch(void* const* d_in, const int* in_sizes, int n_in,
                              void* d_out, int out_size, void* d_ws, size_t ws_size,
                              hipStream_t stream) {
    const float* x    = (const float*)d_in[0];
    const float* wqkv = (const float*)d_in[1];
    const float* bqkv = (const float*)d_in[2];
    const float* wout = (const float*)d_in[3];
    const float* bout = (const float*)d_in[4];
    const float* wff1 = (const float*)d_in[5];
    const float* bff1 = (const float*)d_in[6];
    const float* wff2 = (const float*)d_in[7];
    const float* bff2 = (const float*)d_in[8];
    const float* g1   = (const float*)d_in[9];
    const float* be1  = (const float*)d_in[10];
    const float* g2   = (const float*)d_in[11];
    const float* be2  = (const float*)d_in[12];

    char* ws = (char*)d_ws;
    constexpr size_t o_xb    = 0;
    constexpr size_t o_wqkvT = o_xb    + (size_t)8192 * 768 * 2;
    constexpr size_t o_woutT = o_wqkvT + (size_t)2304 * 768 * 2;
    constexpr size_t o_wff1T = o_woutT + (size_t)768 * 768 * 2;
    constexpr size_t o_wff2T = o_wff1T + (size_t)3072 * 768 * 2;
    constexpr size_t o_qkv   = o_wff2T + (size_t)768 * 3072 * 2;
    constexpr size_t o_ctx   = o_qkv   + (size_t)8192 * 2304 * 2;
    constexpr size_t o_y     = o_ctx   + (size_t)8192 * 768 * 2;
    constexpr size_t o_x1b   = o_y     + (size_t)8192 * 768 * 2;
    constexpr size_t o_vt    = o_x1b;   // vt dead before x1b is written
    constexpr size_t o_h     = o_qkv;   // hb reuses qkv+ctx region

    u16*   xb    = (u16*)(ws + o_xb);
    u16*   wqkvT = (u16*)(ws + o_wqkvT);
    u16*   woutT = (u16*)(ws + o_woutT);
    u16*   wff1T = (u16*)(ws + o_wff1T);
    u16*   wff2T = (u16*)(ws + o_wff2T);
    u16*   qkvb  = (u16*)(ws + o_qkv);
    u16*   ctxb  = (u16*)(ws + o_ctx);
    u16*   yb    = (u16*)(ws + o_y);
    u16*   x1b   = (u16*)(ws + o_x1b);
    u16*   hb    = (u16*)(ws + o_h);
    u16*   vt    = (u16*)(ws + o_vt);

    // fused prologue: x cast + 4 weight transposes
    prep<<<13056, 256, 0, stream>>>(x, xb, wqkv, wqkvT, wout, woutT,
                                    wff1, wff1T, wff2, wff2T);

    // qkv = x @ w_qkv + b ; q (pre-scaled), k -> qkvb bf16, v -> vt transposed
    gemm_bf16<3, 2><<<dim3(2304 / 128, 8192 / 128), 256, 0, stream>>>(
        xb, wqkvT, bqkv, qkvb, vt, 8192, 2304, 768);

    // fused attention -> ctx bf16 [8192, 768]; 768 blocks, XCD-swizzled in-kernel
    attn_fused<<<768, 256, 0, stream>>>(qkvb, vt, ctxb);

    // y = ctx @ w_out + b_out + x  -> bf16
    gemm_bf16_r64<true><<<dim3(768 / 128, 8192 / 64), 256, 0, stream>>>(
        ctxb, woutT, bout, x, yb, 8192, 768, 768);

    // x1 = LN(y) -> bf16 (vt dead after attention)
    layernorm_k<false><<<8192, 256, 0, stream>>>(yb, g1, be1, nullptr, x1b);

    // h = gelu(x1 @ w_ff1 + b_ff1) -> bf16 [8192, 3072]
    gemm_bf16<2, 2><<<dim3(3072 / 128, 8192 / 128), 256, 0, stream>>>(
        x1b, wff1T, bff1, hb, nullptr, 8192, 3072, 768);

    // y2 = h @ w_ff2 + b_ff2 + x1 -> bf16 (yb dead after LN1)
    gemm_bf16_r64<false><<<dim3(768 / 128, 8192 / 64), 256, 0, stream>>>(
        hb, wff2T, bff2, x1b, yb, 8192, 768, 3072);

    // out = LN(y2) -> f32
    layernorm_k<true><<<8192, 256, 0, stream>>>(yb, g2, be2, (float*)d_out, nullptr);
}

// Round 7
// 358.588 us; speedup vs baseline: 1.3539x; 1.0261x over previous
//
#include <hip/hip_runtime.h>
#include <cstdint>
#include <cstddef>

typedef unsigned short u16;
typedef __attribute__((ext_vector_type(8))) short bf16x8;    // 8 bf16 = 4 VGPRs
typedef __attribute__((ext_vector_type(4))) float f32x4;     // 16x16 C/D
typedef __attribute__((ext_vector_type(16))) float f32x16;   // 32x32 C/D

// ---------- helpers ----------
__device__ __forceinline__ u16 f2b(float f) {
    union { float f; unsigned u; } un; un.f = f;
    unsigned r = un.u + 0x7fffu + ((un.u >> 16) & 1u);   // RNE
    return (u16)(r >> 16);
}
__device__ __forceinline__ float b2f(u16 h) {
    union { unsigned u; float f; } un; un.u = ((unsigned)h) << 16;
    return un.f;
}
__device__ __forceinline__ float fast_exp2(float x) {
#if __has_builtin(__builtin_amdgcn_exp2f)
    return __builtin_amdgcn_exp2f(x);
#else
    return exp2f(x);
#endif
}
__device__ __forceinline__ float fast_rcp(float x) {
#if __has_builtin(__builtin_amdgcn_rcpf)
    return __builtin_amdgcn_rcpf(x);
#else
    return 1.f / x;
#endif
}
// tanh-form GELU via exp2: v * s/(s+1), s = 2^(v*(a + b v^2)).
__device__ __forceinline__ float gelu_fast(float v) {
    const float s = fast_exp2(v * (2.30220842f + 0.10294324f * (v * v)));
    return v - v * fast_rcp(s + 1.f);      // s=inf -> rcp->0 -> v (no NaN)
}

// async global->LDS DMA, 16B per lane (wave-uniform base + lane*16 semantics).
__device__ __forceinline__ void stage16(const u16* g, u16* l) {
    __builtin_amdgcn_global_load_lds(
        (const __attribute__((address_space(1))) void*)g,
        (__attribute__((address_space(3))) void*)l, 16, 0, 0);
}

// ---------- fused prologue: x cast + 4 weight transposes ----------
__global__ __launch_bounds__(256)
void prep(const float* __restrict__ x, u16* __restrict__ xb,
          const float* __restrict__ wqkv, u16* __restrict__ wqkvT,
          const float* __restrict__ wout, u16* __restrict__ woutT,
          const float* __restrict__ wff1, u16* __restrict__ wff1T,
          const float* __restrict__ wff2, u16* __restrict__ wff2T) {
    __shared__ float t[32][33];
    const int tid = threadIdx.x;
    int bid = blockIdx.x;
    if (bid < 6144) {
        const int i = bid * 256 + tid;
        float4 v = ((const float4*)x)[i];
        ushort4 o;
        o.x = f2b(v.x); o.y = f2b(v.y); o.z = f2b(v.z); o.w = f2b(v.w);
        ((ushort4*)xb)[i] = o;
        return;
    }
    int tt = bid - 6144;
    const float* in; u16* out; int K, N, bx, by;
    if (tt < 1728)      { in = wqkv; out = wqkvT; K = 768;  N = 2304; bx = tt % 72; by = tt / 72; }
    else if ((tt -= 1728) < 576)  { in = wout; out = woutT; K = 768;  N = 768;  bx = tt % 24; by = tt / 24; }
    else if ((tt -= 576) < 2304)  { in = wff1; out = wff1T; K = 768;  N = 3072; bx = tt % 96; by = tt / 96; }
    else { tt -= 2304;    in = wff2; out = wff2T; K = 3072; N = 768;  bx = tt % 24; by = tt / 24; }
    const int n0 = bx * 32, k0 = by * 32;
    const int tx = tid & 31, ty = tid >> 5;     // 32 x 8
#pragma unroll
    for (int i = 0; i < 4; ++i)
        t[ty + i * 8][tx] = in[(size_t)(k0 + ty + i * 8) * N + n0 + tx];
    __syncthreads();
#pragma unroll
    for (int i = 0; i < 4; ++i)
        out[(size_t)(n0 + ty + i * 8) * K + k0 + tx] = f2b(t[tx][ty + i * 8]);
}

// ---------- GEMM 128 x (NTW*64), 32x32x16 MFMA ----------
// EPI 2: bf16 out = gelu(acc + bias)
// EPI 3: qkv: cols<768 -> q * softmax-scale; 768..1535 -> k; >=1536 -> vt transposed
template <int EPI, int NTW>
__global__ __launch_bounds__(256, 3)
void gemm_bf16(const u16* __restrict__ A, const u16* __restrict__ BT,
               const float* __restrict__ bias,
               void* __restrict__ outp, u16* __restrict__ vt, int M, int N, int K) {
    __shared__ __align__(16) u16 Ash[128 * 64];
    __shared__ __align__(16) u16 Bsh[NTW * 64 * 64];
    const int m0 = blockIdx.y * 128, n0 = blockIdx.x * (NTW * 64);
    const int tid = threadIdx.x;
    const int w = tid >> 6, lane = tid & 63;
    const int l32 = lane & 31, half = lane >> 5;
    const int wm = (w >> 1) * 64, wn = (w & 1) * (NTW * 32);

    const int srow = lane >> 3;
    const int sgrp = (lane & 7) ^ (srow & 7);
    const int xr = l32 & 7;                       // read-side swizzle key (= row&7)

    f32x16 acc[2][NTW];
#pragma unroll
    for (int i = 0; i < 2; ++i)
#pragma unroll
        for (int j = 0; j < NTW; ++j)
#pragma unroll
            for (int e = 0; e < 16; ++e) acc[i][j][e] = 0.f;

    for (int k0 = 0; k0 < K; k0 += 64) {
#pragma unroll
        for (int it = 0; it < 4; ++it) {
            const int c = it * 4 + w;
            const int r = c * 8 + srow;
            stage16(A + (size_t)(m0 + r) * K + k0 + sgrp * 8, &Ash[c * 512 + lane * 8]);
        }
#pragma unroll
        for (int it = 0; it < 2 * NTW; ++it) {
            const int c = it * 4 + w;
            const int r = c * 8 + srow;
            stage16(BT + (size_t)(n0 + r) * K + k0 + sgrp * 8, &Bsh[c * 512 + lane * 8]);
        }
        __syncthreads();

        if constexpr (NTW == 2) {
            bf16x8 af[2][4], bfr[2][4];
#pragma unroll
            for (int mt = 0; mt < 2; ++mt)
#pragma unroll
                for (int kc = 0; kc < 4; ++kc)
                    af[mt][kc] = *(const bf16x8*)&Ash[(wm + mt * 32 + l32) * 64 +
                                                      (((kc << 1) + half) ^ xr) * 8];
#pragma unroll
            for (int nt = 0; nt < 2; ++nt)
#pragma unroll
                for (int kc = 0; kc < 4; ++kc)
                    bfr[nt][kc] = *(const bf16x8*)&Bsh[(wn + nt * 32 + l32) * 64 +
                                                       (((kc << 1) + half) ^ xr) * 8];
#pragma unroll
            for (int mt = 0; mt < 2; ++mt)
#pragma unroll
                for (int nt = 0; nt < 2; ++nt)
#pragma unroll
                    for (int kc = 0; kc < 4; ++kc)
                        acc[mt][nt] = __builtin_amdgcn_mfma_f32_32x32x16_bf16(
                            af[mt][kc], bfr[nt][kc], acc[mt][nt], 0, 0, 0);
        } else {
#pragma unroll
            for (int kc = 0; kc < 4; ++kc) {
                const int ko = (((kc << 1) + half) ^ xr) * 8;
                bf16x8 a0 = *(const bf16x8*)&Ash[(wm + l32) * 64 + ko];
                bf16x8 a1 = *(const bf16x8*)&Ash[(wm + 32 + l32) * 64 + ko];
#pragma unroll
                for (int nt = 0; nt < NTW; ++nt) {
                    bf16x8 bv = *(const bf16x8*)&Bsh[(wn + nt * 32 + l32) * 64 + ko];
                    acc[0][nt] = __builtin_amdgcn_mfma_f32_32x32x16_bf16(
                        a0, bv, acc[0][nt], 0, 0, 0);
                    acc[1][nt] = __builtin_amdgcn_mfma_f32_32x32x16_bf16(
                        a1, bv, acc[1][nt], 0, 0, 0);
                }
            }
        }
        __syncthreads();
    }

    if (EPI == 3 && n0 >= 1536) {
#pragma unroll
        for (int mt = 0; mt < 2; ++mt) {
#pragma unroll
            for (int nt = 0; nt < NTW; ++nt) {
                const int col = n0 + wn + nt * 32 + l32;
                const int c = col - 1536;
                const int h = c >> 6, d = c & 63;
                const float bv = bias[col];
#pragma unroll
                for (int rq = 0; rq < 4; ++rq) {
                    const int row0 = m0 + wm + mt * 32 + rq * 8 + half * 4;
                    const int b = row0 >> 11, tok = row0 & 2047;
                    ushort4 o;
                    o.x = f2b(acc[mt][nt][rq * 4 + 0] + bv);
                    o.y = f2b(acc[mt][nt][rq * 4 + 1] + bv);
                    o.z = f2b(acc[mt][nt][rq * 4 + 2] + bv);
                    o.w = f2b(acc[mt][nt][rq * 4 + 3] + bv);
                    *(ushort4*)&vt[(size_t)(((b * 12 + h) << 6) + d) * 2048 + tok] = o;
                }
            }
        }
        return;
    }

#pragma unroll
    for (int mt = 0; mt < 2; ++mt) {
#pragma unroll
        for (int nt = 0; nt < NTW; ++nt) {
            const int col = n0 + wn + nt * 32 + l32;
            const float bv = bias[col];
#pragma unroll
            for (int reg = 0; reg < 16; ++reg) {
                const int row = m0 + wm + mt * 32 + (reg & 3) + 8 * (reg >> 2) + 4 * half;
                float v = acc[mt][nt][reg] + bv;
                if (EPI == 2)
                    v = gelu_fast(v);
                if (EPI == 3 && col < 768)
                    v *= 0.18033688011112042f;   // fold log2(e)/8 into q
                ((u16*)outp)[(size_t)row * N + col] = f2b(v);
            }
        }
    }
}

// ---------- GEMM 64x128 (32x32x16), bf16 out = acc + bias + resid ----------
template <bool RESF32>
__global__ __launch_bounds__(256, 4)
void gemm_bf16_r64(const u16* __restrict__ A, const u16* __restrict__ BT,
                   const float* __restrict__ bias, const void* __restrict__ resid,
                   u16* __restrict__ outp, int M, int N, int K) {
    __shared__ __align__(16) u16 Ash[64 * 64];
    __shared__ __align__(16) u16 Bsh[128 * 64];
    const int m0 = blockIdx.y * 64, n0 = blockIdx.x * 128;
    const int tid = threadIdx.x;
    const int w = tid >> 6, lane = tid & 63;
    const int l32 = lane & 31, half = lane >> 5;
    const int wm = (w >> 1) * 32, wn = (w & 1) * 64;

    const int srow = lane >> 3;
    const int sgrp = (lane & 7) ^ (srow & 7);
    const int xr = l32 & 7;

    f32x16 acc[2];
#pragma unroll
    for (int j = 0; j < 2; ++j)
#pragma unroll
        for (int e = 0; e < 16; ++e) acc[j][e] = 0.f;

    for (int k0 = 0; k0 < K; k0 += 64) {
#pragma unroll
        for (int it = 0; it < 2; ++it) {
            const int c = it * 4 + w;
            const int r = c * 8 + srow;
            stage16(A + (size_t)(m0 + r) * K + k0 + sgrp * 8, &Ash[c * 512 + lane * 8]);
        }
#pragma unroll
        for (int it = 0; it < 4; ++it) {
            const int c = it * 4 + w;
            const int r = c * 8 + srow;
            stage16(BT + (size_t)(n0 + r) * K + k0 + sgrp * 8, &Bsh[c * 512 + lane * 8]);
        }
        __syncthreads();

        bf16x8 af[4], bfr[2][4];
#pragma unroll
        for (int kc = 0; kc < 4; ++kc)
            af[kc] = *(const bf16x8*)&Ash[(wm + l32) * 64 + (((kc << 1) + half) ^ xr) * 8];
#pragma unroll
        for (int nt = 0; nt < 2; ++nt)
#pragma unroll
            for (int kc = 0; kc < 4; ++kc)
                bfr[nt][kc] = *(const bf16x8*)&Bsh[(wn + nt * 32 + l32) * 64 +
                                                   (((kc << 1) + half) ^ xr) * 8];
#pragma unroll
        for (int nt = 0; nt < 2; ++nt)
#pragma unroll
            for (int kc = 0; kc < 4; ++kc)
                acc[nt] = __builtin_amdgcn_mfma_f32_32x32x16_bf16(
                    af[kc], bfr[nt][kc], acc[nt], 0, 0, 0);
        __syncthreads();
    }

#pragma unroll
    for (int nt = 0; nt < 2; ++nt) {
        const int col = n0 + wn + nt * 32 + l32;
        const float bv = bias[col];
#pragma unroll
        for (int reg = 0; reg < 16; ++reg) {
            const int row = m0 + wm + (reg & 3) + 8 * (reg >> 2) + 4 * half;
            const size_t idx = (size_t)row * N + col;
            const float rv = RESF32 ? ((const float*)resid)[idx]
                                    : b2f(((const u16*)resid)[idx]);
            outp[idx] = f2b(acc[nt][reg] + bv + rv);
        }
    }
}

// ---------- fused flash attention v7: per-nt register-lean schedule ----------
// Same math/layout as v6 (32x32 swapped QK^T, in-register P via cvt_pk +
// permlane32_swap, Q pre-scaled). Fragments are loaded per-nt just-in-time to
// cut peak live registers (~40 VGPRs) so 3 blocks/CU fit -> grid = 1 round.
__global__ __launch_bounds__(256, 3)
void attn_fused(const u16* __restrict__ qkv, const u16* __restrict__ vt,
                u16* __restrict__ ctx) {
    __shared__ __align__(16) u16 Ksh[2][64 * 64];   // [tok][d]
    __shared__ __align__(16) u16 Vsh[2][64 * 64];   // [d][tok]

    // bijective XCD swizzle: all 16 q-tiles of one (b,h) on one XCD's L2
    const int orig = blockIdx.x;                  // 0..767
    const int swz = (orig & 7) * 96 + (orig >> 3);
    const int q0 = (swz & 15) * 128;
    const int bh = swz >> 4;                      // 0..47
    const int h = bh % 12, b = bh / 12;

    const int tid = threadIdx.x;
    const int w = tid >> 6, lane = tid & 63;
    const int l32 = lane & 31, hi5 = lane >> 5;
    const int xr8 = l32 & 7;                      // read-side swizzle key (= row&7)

    const int srow = lane >> 3;
    const int sgrp = (lane & 7) ^ (srow & 7);

    const u16* Qp = qkv + (size_t)b * 2048 * 2304 + h * 64;
    const u16* Kp = Qp + 768;
    const u16* Vtp = vt + ((size_t)(b * 12 + h) << 6) * 2048;

    // Q as B-operand (32x32x16): lane holds col q=l32, k-elems d = ks*16+hi5*8..+7
    bf16x8 qf[4];
#pragma unroll
    for (int ks = 0; ks < 4; ++ks)
        qf[ks] = *(const bf16x8*)(Qp +
            (size_t)(q0 + w * 32 + l32) * 2304 + ks * 16 + hi5 * 8);
    // drain Q loads so manual vmcnt bookkeeping below is exact
    asm volatile("s_waitcnt vmcnt(0)" ::: "memory");
    __builtin_amdgcn_sched_barrier(0);

    f32x16 oacc[2];
#pragma unroll
    for (int dt = 0; dt < 2; ++dt)
#pragma unroll
        for (int e = 0; e < 16; ++e) oacc[dt][e] = 0.f;
    float ls0 = 0.f, ls1 = 0.f, ls2 = 0.f, ls3 = 0.f;

    // 4 stage16 per wave per tile (2 K + 2 V)
    auto stage_kv = [&](int buf, int ktt) {
#pragma unroll
        for (int it = 0; it < 2; ++it) {
            const int c = it * 4 + w;
            const int r = c * 8 + srow;
            stage16(Kp + (size_t)(ktt + r) * 2304 + sgrp * 8,
                    &Ksh[buf][c * 512 + lane * 8]);
        }
#pragma unroll
        for (int it = 0; it < 2; ++it) {
            const int c = it * 4 + w;
            const int r = c * 8 + srow;      // r = d
            stage16(Vtp + (size_t)r * 2048 + ktt + sgrp * 8,
                    &Vsh[buf][c * 512 + lane * 8]);
        }
    };

    stage_kv(0, 0);

    for (int t = 0; t < 32; ++t) {
        const int cur = t & 1;
        if (t < 31) {
            stage_kv(cur ^ 1, (t + 1) * 64);
            asm volatile("s_waitcnt vmcnt(4)" ::: "memory");  // cur tile landed
        } else {
            asm volatile("s_waitcnt vmcnt(0)" ::: "memory");
        }
        __builtin_amdgcn_sched_barrier(0);
        __builtin_amdgcn_s_barrier();

#pragma unroll
        for (int nt = 0; nt < 2; ++nt) {
            // ---- K fragments (transient) + QK^T (swapped): S[tok][q] ----
            bf16x8 kfr[4];
#pragma unroll
            for (int ks = 0; ks < 4; ++ks)
                kfr[ks] = *(const bf16x8*)&Ksh[cur][(nt * 32 + l32) * 64 +
                                                   (((ks << 1) + hi5) ^ xr8) * 8];

            f32x16 sacc;
#pragma unroll
            for (int e = 0; e < 16; ++e) sacc[e] = 0.f;

            __builtin_amdgcn_s_setprio(1);
#pragma unroll
            for (int ks = 0; ks < 4; ++ks)
                sacc = __builtin_amdgcn_mfma_f32_32x32x16_bf16(
                    kfr[ks], qf[ks], sacc, 0, 0, 0);
            __builtin_amdgcn_s_setprio(0);

            // ---- this nt's V fragments early: latency hides under softmax ----
            bf16x8 vfr[4];   // [dt*2 + kh]
#pragma unroll
            for (int dt = 0; dt < 2; ++dt)
#pragma unroll
                for (int kh = 0; kh < 2; ++kh)
                    vfr[dt * 2 + kh] = *(const bf16x8*)&Vsh[cur][
                        (dt * 32 + l32) * 64 +
                        ((((nt << 2) + (kh << 1) + hi5) ^ xr8) * 8)];

            // ---- softmax (max-free, Q pre-scaled): exp2 + lane-local sums ----
#pragma unroll
            for (int e = 0; e < 16; ++e)
                sacc[e] = fast_exp2(sacc[e]);
            ls0 += (sacc[0] + sacc[1]) + (sacc[8] + sacc[9]);
            ls1 += (sacc[2] + sacc[3]) + (sacc[10] + sacc[11]);
            ls2 += (sacc[4] + sacc[5]) + (sacc[12] + sacc[13]);
            ls3 += (sacc[6] + sacc[7]) + (sacc[14] + sacc[15]);

            // ---- pack P (cvt_pk + permlane32_swap) and PV accumulate ----
            __builtin_amdgcn_s_setprio(1);
#pragma unroll
            for (int kh = 0; kh < 2; ++kh) {      // 16-token k-step
                const int rb = kh * 8;
                unsigned c01, c23, c45, c67;
                asm("v_cvt_pk_bf16_f32 %0, %1, %2"
                    : "=v"(c01) : "v"(sacc[rb + 0]), "v"(sacc[rb + 1]));
                asm("v_cvt_pk_bf16_f32 %0, %1, %2"
                    : "=v"(c23) : "v"(sacc[rb + 2]), "v"(sacc[rb + 3]));
                asm("v_cvt_pk_bf16_f32 %0, %1, %2"
                    : "=v"(c45) : "v"(sacc[rb + 4]), "v"(sacc[rb + 5]));
                asm("v_cvt_pk_bf16_f32 %0, %1, %2"
                    : "=v"(c67) : "v"(sacc[rb + 6]), "v"(sacc[rb + 7]));
                // lane<32 <-> lane>=32 half exchange: fills tokens hi5*8..+7 in order
                asm("v_permlane32_swap_b32 %0, %1" : "+v"(c01), "+v"(c45));
                asm("v_permlane32_swap_b32 %0, %1" : "+v"(c23), "+v"(c67));
                union { unsigned u[4]; bf16x8 v; } pf;
                pf.u[0] = c01; pf.u[1] = c23; pf.u[2] = c45; pf.u[3] = c67;
#pragma unroll
                for (int dt = 0; dt < 2; ++dt)
                    oacc[dt] = __builtin_amdgcn_mfma_f32_32x32x16_bf16(
                        pf.v, vfr[dt * 2 + kh], oacc[dt], 0, 0, 0);
            }
            __builtin_amdgcn_s_setprio(0);
        }
        __builtin_amdgcn_s_barrier();
    }

    // row sum: lane q=l32 holds half the tokens; partner (lane^32) has the rest
    float lsum = (ls0 + ls1) + (ls2 + ls3);
    lsum += __shfl_xor(lsum, 32);
    const float linv = 1.f / lsum;

    // per-output-row scale: row q_r's sum lives on lane q_r
    float scv[16];
#pragma unroll
    for (int reg = 0; reg < 16; ++reg) {
        const int q_r = (reg & 3) + 8 * (reg >> 2) + 4 * hi5;
        scv[reg] = __shfl(linv, q_r);
    }

#pragma unroll
    for (int dt = 0; dt < 2; ++dt)
#pragma unroll
        for (int reg = 0; reg < 16; ++reg) {
            const int q_r = (reg & 3) + 8 * (reg >> 2) + 4 * hi5;
            const int row = q0 + w * 32 + q_r;
            ctx[(size_t)(b * 2048 + row) * 768 + h * 64 + dt * 32 + l32] =
                f2b(oacc[dt][reg] * scv[reg]);
        }
}

// ---------- LayerNorm over H=768 (bf16 in); OUTF32 ? f32 out : bf16 out ----------
template <bool OUTF32>
__global__ __launch_bounds__(256)
void layernorm_k(const u16* __restrict__ y, const float* __restrict__ g,
                 const float* __restrict__ be, float* __restrict__ outf,
                 u16* __restrict__ outb) {
    const int row = blockIdx.x;
    const int tid = threadIdx.x;
    const u16* yr = y + (size_t)row * 768;
    float v[3], s = 0.f, s2 = 0.f;
#pragma unroll
    for (int i = 0; i < 3; ++i) {
        float x = b2f(yr[tid + i * 256]);
        v[i] = x; s += x; s2 += x * x;
    }
#pragma unroll
    for (int off = 32; off >= 1; off >>= 1) {
        s += __shfl_xor(s, off);
        s2 += __shfl_xor(s2, off);
    }
    __shared__ float red[2][4];
    const int w = tid >> 6;
    if ((tid & 63) == 0) { red[0][w] = s; red[1][w] = s2; }
    __syncthreads();
    s = red[0][0] + red[0][1] + red[0][2] + red[0][3];
    s2 = red[1][0] + red[1][1] + red[1][2] + red[1][3];
    const float mu = s * (1.f / 768.f);
    const float var = s2 * (1.f / 768.f) - mu * mu;
    const float rs = rsqrtf(var + 1e-12f);
#pragma unroll
    for (int i = 0; i < 3; ++i) {
        const int c = tid + i * 256;
        const float o = (v[i] - mu) * rs * g[c] + be[c];
        if (OUTF32) outf[(size_t)row * 768 + c] = o;
        else        outb[(size_t)row * 768 + c] = f2b(o);
    }
}

// ---------- orchestration ----------
extern "C" void kernel_launch(void* const* d_in, const int* in_sizes, int n_in,
                              void* d_out, int out_size, void* d_ws, size_t ws_size,
                              hipStream_t stream) {
    const float* x    = (const float*)d_in[0];
    const float* wqkv = (const float*)d_in[1];
    const float* bqkv = (const float*)d_in[2];
    const float* wout = (const float*)d_in[3];
    const float* bout = (const float*)d_in[4];
    const float* wff1 = (const float*)d_in[5];
    const float* bff1 = (const float*)d_in[6];
    const float* wff2 = (const float*)d_in[7];
    const float* bff2 = (const float*)d_in[8];
    const float* g1   = (const float*)d_in[9];
    const float* be1  = (const float*)d_in[10];
    const float* g2   = (const float*)d_in[11];
    const float* be2  = (const float*)d_in[12];

    char* ws = (char*)d_ws;
    constexpr size_t o_xb    = 0;
    constexpr size_t o_wqkvT = o_xb    + (size_t)8192 * 768 * 2;
    constexpr size_t o_woutT = o_wqkvT + (size_t)2304 * 768 * 2;
    constexpr size_t o_wff1T = o_woutT + (size_t)768 * 768 * 2;
    constexpr size_t o_wff2T = o_wff1T + (size_t)3072 * 768 * 2;
    constexpr size_t o_qkv   = o_wff2T + (size_t)768 * 3072 * 2;
    constexpr size_t o_ctx   = o_qkv   + (size_t)8192 * 2304 * 2;
    constexpr size_t o_y     = o_ctx   + (size_t)8192 * 768 * 2;
    constexpr size_t o_x1b   = o_y     + (size_t)8192 * 768 * 2;
    constexpr size_t o_vt    = o_x1b;   // vt dead before x1b is written
    constexpr size_t o_h     = o_qkv;   // hb reuses qkv+ctx region

    u16*   xb    = (u16*)(ws + o_xb);
    u16*   wqkvT = (u16*)(ws + o_wqkvT);
    u16*   woutT = (u16*)(ws + o_woutT);
    u16*   wff1T = (u16*)(ws + o_wff1T);
    u16*   wff2T = (u16*)(ws + o_wff2T);
    u16*   qkvb  = (u16*)(ws + o_qkv);
    u16*   ctxb  = (u16*)(ws + o_ctx);
    u16*   yb    = (u16*)(ws + o_y);
    u16*   x1b   = (u16*)(ws + o_x1b);
    u16*   hb    = (u16*)(ws + o_h);
    u16*   vt    = (u16*)(ws + o_vt);

    // fused prologue: x cast + 4 weight transposes
    prep<<<13056, 256, 0, stream>>>(x, xb, wqkv, wqkvT, wout, woutT,
                                    wff1, wff1T, wff2, wff2T);

    // qkv = x @ w_qkv + b ; q (pre-scaled), k -> qkvb bf16, v -> vt transposed
    // 192-wide tile: grid = 12*64 = 768 blocks = one round at 3/CU (measured faster)
    gemm_bf16<3, 3><<<dim3(2304 / 192, 8192 / 128), 256, 0, stream>>>(
        xb, wqkvT, bqkv, qkvb, vt, 8192, 2304, 768);

    // fused attention -> ctx bf16 [8192, 768]; 768 blocks, XCD-swizzled in-kernel
    attn_fused<<<768, 256, 0, stream>>>(qkvb, vt, ctxb);

    // y = ctx @ w_out + b_out + x  -> bf16
    gemm_bf16_r64<true><<<dim3(768 / 128, 8192 / 64), 256, 0, stream>>>(
        ctxb, woutT, bout, x, yb, 8192, 768, 768);

    // x1 = LN(y) -> bf16 (vt dead after attention)
    layernorm_k<false><<<8192, 256, 0, stream>>>(yb, g1, be1, nullptr, x1b);

    // h = gelu(x1 @ w_ff1 + b_ff1) -> bf16 [8192, 3072]
    gemm_bf16<2, 2><<<dim3(3072 / 128, 8192 / 128), 256, 0, stream>>>(
        x1b, wff1T, bff1, hb, nullptr, 8192, 3072, 768);

    // y2 = h @ w_ff2 + b_ff2 + x1 -> bf16 (yb dead after LN1)
    gemm_bf16_r64<false><<<dim3(768 / 128, 8192 / 64), 256, 0, stream>>>(
        hb, wff2T, bff2, x1b, yb, 8192, 768, 3072);

    // out = LN(y2) -> f32
    layernorm_k<true><<<8192, 256, 0, stream>>>(yb, g2, be2, (float*)d_out, nullptr);
}

// Round 8
// 344.434 us; speedup vs baseline: 1.4096x; 1.0411x over previous
//
#include <hip/hip_runtime.h>
#include <cstdint>
#include <cstddef>

typedef unsigned short u16;
typedef __attribute__((ext_vector_type(8))) short bf16x8;    // 8 bf16 = 4 VGPRs
typedef __attribute__((ext_vector_type(4))) float f32x4;     // 16x16 C/D
typedef __attribute__((ext_vector_type(16))) float f32x16;   // 32x32 C/D

// ---------- helpers ----------
__device__ __forceinline__ u16 f2b(float f) {
    union { float f; unsigned u; } un; un.f = f;
    unsigned r = un.u + 0x7fffu + ((un.u >> 16) & 1u);   // RNE
    return (u16)(r >> 16);
}
__device__ __forceinline__ float b2f(u16 h) {
    union { unsigned u; float f; } un; un.u = ((unsigned)h) << 16;
    return un.f;
}
__device__ __forceinline__ float fast_exp2(float x) {
#if __has_builtin(__builtin_amdgcn_exp2f)
    return __builtin_amdgcn_exp2f(x);
#else
    return exp2f(x);
#endif
}
__device__ __forceinline__ float fast_rcp(float x) {
#if __has_builtin(__builtin_amdgcn_rcpf)
    return __builtin_amdgcn_rcpf(x);
#else
    return 1.f / x;
#endif
}
// tanh-form GELU via exp2: v * s/(s+1), s = 2^(v*(a + b v^2)).
__device__ __forceinline__ float gelu_fast(float v) {
    const float s = fast_exp2(v * (2.30220842f + 0.10294324f * (v * v)));
    return v - v * fast_rcp(s + 1.f);      // s=inf -> rcp->0 -> v (no NaN)
}

// async global->LDS DMA, 16B per lane (wave-uniform base + lane*16 semantics).
__device__ __forceinline__ void stage16(const u16* g, u16* l) {
    __builtin_amdgcn_global_load_lds(
        (const __attribute__((address_space(1))) void*)g,
        (__attribute__((address_space(3))) void*)l, 16, 0, 0);
}

// ---------- fused prologue: x cast + 4 weight transposes ----------
__global__ __launch_bounds__(256)
void prep(const float* __restrict__ x, u16* __restrict__ xb,
          const float* __restrict__ wqkv, u16* __restrict__ wqkvT,
          const float* __restrict__ wout, u16* __restrict__ woutT,
          const float* __restrict__ wff1, u16* __restrict__ wff1T,
          const float* __restrict__ wff2, u16* __restrict__ wff2T) {
    __shared__ float t[32][33];
    const int tid = threadIdx.x;
    int bid = blockIdx.x;
    if (bid < 6144) {
        const int i = bid * 256 + tid;
        float4 v = ((const float4*)x)[i];
        ushort4 o;
        o.x = f2b(v.x); o.y = f2b(v.y); o.z = f2b(v.z); o.w = f2b(v.w);
        ((ushort4*)xb)[i] = o;
        return;
    }
    int tt = bid - 6144;
    const float* in; u16* out; int K, N, bx, by;
    if (tt < 1728)      { in = wqkv; out = wqkvT; K = 768;  N = 2304; bx = tt % 72; by = tt / 72; }
    else if ((tt -= 1728) < 576)  { in = wout; out = woutT; K = 768;  N = 768;  bx = tt % 24; by = tt / 24; }
    else if ((tt -= 576) < 2304)  { in = wff1; out = wff1T; K = 768;  N = 3072; bx = tt % 96; by = tt / 96; }
    else { tt -= 2304;    in = wff2; out = wff2T; K = 3072; N = 768;  bx = tt % 24; by = tt / 24; }
    const int n0 = bx * 32, k0 = by * 32;
    const int tx = tid & 31, ty = tid >> 5;     // 32 x 8
#pragma unroll
    for (int i = 0; i < 4; ++i)
        t[ty + i * 8][tx] = in[(size_t)(k0 + ty + i * 8) * N + n0 + tx];
    __syncthreads();
#pragma unroll
    for (int i = 0; i < 4; ++i)
        out[(size_t)(n0 + ty + i * 8) * K + k0 + tx] = f2b(t[tx][ty + i * 8]);
}

// ---------- GEMM 128 x (NTW*64), 32x32x16 MFMA ----------
// EPI 2: bf16 out = gelu(acc + bias)
// EPI 3: qkv: cols<768 -> q * softmax-scale; 768..1535 -> k; >=1536 -> vt transposed
template <int EPI, int NTW>
__global__ __launch_bounds__(256, 3)
void gemm_bf16(const u16* __restrict__ A, const u16* __restrict__ BT,
               const float* __restrict__ bias,
               void* __restrict__ outp, u16* __restrict__ vt, int M, int N, int K) {
    __shared__ __align__(16) u16 Ash[128 * 64];
    __shared__ __align__(16) u16 Bsh[NTW * 64 * 64];
    const int m0 = blockIdx.y * 128, n0 = blockIdx.x * (NTW * 64);
    const int tid = threadIdx.x;
    const int w = tid >> 6, lane = tid & 63;
    const int l32 = lane & 31, half = lane >> 5;
    const int wm = (w >> 1) * 64, wn = (w & 1) * (NTW * 32);

    const int srow = lane >> 3;
    const int sgrp = (lane & 7) ^ (srow & 7);
    const int xr = l32 & 7;                       // read-side swizzle key (= row&7)

    f32x16 acc[2][NTW];
#pragma unroll
    for (int i = 0; i < 2; ++i)
#pragma unroll
        for (int j = 0; j < NTW; ++j)
#pragma unroll
            for (int e = 0; e < 16; ++e) acc[i][j][e] = 0.f;

    for (int k0 = 0; k0 < K; k0 += 64) {
#pragma unroll
        for (int it = 0; it < 4; ++it) {
            const int c = it * 4 + w;
            const int r = c * 8 + srow;
            stage16(A + (size_t)(m0 + r) * K + k0 + sgrp * 8, &Ash[c * 512 + lane * 8]);
        }
#pragma unroll
        for (int it = 0; it < 2 * NTW; ++it) {
            const int c = it * 4 + w;
            const int r = c * 8 + srow;
            stage16(BT + (size_t)(n0 + r) * K + k0 + sgrp * 8, &Bsh[c * 512 + lane * 8]);
        }
        __syncthreads();

        if constexpr (NTW == 2) {
            bf16x8 af[2][4], bfr[2][4];
#pragma unroll
            for (int mt = 0; mt < 2; ++mt)
#pragma unroll
                for (int kc = 0; kc < 4; ++kc)
                    af[mt][kc] = *(const bf16x8*)&Ash[(wm + mt * 32 + l32) * 64 +
                                                      (((kc << 1) + half) ^ xr) * 8];
#pragma unroll
            for (int nt = 0; nt < 2; ++nt)
#pragma unroll
                for (int kc = 0; kc < 4; ++kc)
                    bfr[nt][kc] = *(const bf16x8*)&Bsh[(wn + nt * 32 + l32) * 64 +
                                                       (((kc << 1) + half) ^ xr) * 8];
#pragma unroll
            for (int mt = 0; mt < 2; ++mt)
#pragma unroll
                for (int nt = 0; nt < 2; ++nt)
#pragma unroll
                    for (int kc = 0; kc < 4; ++kc)
                        acc[mt][nt] = __builtin_amdgcn_mfma_f32_32x32x16_bf16(
                            af[mt][kc], bfr[nt][kc], acc[mt][nt], 0, 0, 0);
        } else {
#pragma unroll
            for (int kc = 0; kc < 4; ++kc) {
                const int ko = (((kc << 1) + half) ^ xr) * 8;
                bf16x8 a0 = *(const bf16x8*)&Ash[(wm + l32) * 64 + ko];
                bf16x8 a1 = *(const bf16x8*)&Ash[(wm + 32 + l32) * 64 + ko];
#pragma unroll
                for (int nt = 0; nt < NTW; ++nt) {
                    bf16x8 bv = *(const bf16x8*)&Bsh[(wn + nt * 32 + l32) * 64 + ko];
                    acc[0][nt] = __builtin_amdgcn_mfma_f32_32x32x16_bf16(
                        a0, bv, acc[0][nt], 0, 0, 0);
                    acc[1][nt] = __builtin_amdgcn_mfma_f32_32x32x16_bf16(
                        a1, bv, acc[1][nt], 0, 0, 0);
                }
            }
        }
        __syncthreads();
    }

    if (EPI == 3 && n0 >= 1536) {
#pragma unroll
        for (int mt = 0; mt < 2; ++mt) {
#pragma unroll
            for (int nt = 0; nt < NTW; ++nt) {
                const int col = n0 + wn + nt * 32 + l32;
                const int c = col - 1536;
                const int h = c >> 6, d = c & 63;
                const float bv = bias[col];
#pragma unroll
                for (int rq = 0; rq < 4; ++rq) {
                    const int row0 = m0 + wm + mt * 32 + rq * 8 + half * 4;
                    const int b = row0 >> 11, tok = row0 & 2047;
                    ushort4 o;
                    o.x = f2b(acc[mt][nt][rq * 4 + 0] + bv);
                    o.y = f2b(acc[mt][nt][rq * 4 + 1] + bv);
                    o.z = f2b(acc[mt][nt][rq * 4 + 2] + bv);
                    o.w = f2b(acc[mt][nt][rq * 4 + 3] + bv);
                    *(ushort4*)&vt[(size_t)(((b * 12 + h) << 6) + d) * 2048 + tok] = o;
                }
            }
        }
        return;
    }

#pragma unroll
    for (int mt = 0; mt < 2; ++mt) {
#pragma unroll
        for (int nt = 0; nt < NTW; ++nt) {
            const int col = n0 + wn + nt * 32 + l32;
            const float bv = bias[col];
#pragma unroll
            for (int reg = 0; reg < 16; ++reg) {
                const int row = m0 + wm + mt * 32 + (reg & 3) + 8 * (reg >> 2) + 4 * half;
                float v = acc[mt][nt][reg] + bv;
                if (EPI == 2)
                    v = gelu_fast(v);
                if (EPI == 3 && col < 768)
                    v *= 0.18033688011112042f;   // fold log2(e)/8 into q
                ((u16*)outp)[(size_t)row * N + col] = f2b(v);
            }
        }
    }
}

// ---------- GEMM 64x128 (32x32x16), bf16 out = acc + bias + resid ----------
// v8: double-buffered LDS + counted vmcnt (HBM-latency regime), XCD-affinity
// swizzle so the 6 column-blocks sharing an A-row-strip land on one XCD's L2.
template <bool RESF32>
__global__ __launch_bounds__(256, 3)
void gemm_bf16_r64(const u16* __restrict__ A, const u16* __restrict__ BT,
                   const float* __restrict__ bias, const void* __restrict__ resid,
                   u16* __restrict__ outp, int M, int N, int K) {
    __shared__ __align__(16) u16 Ash[2][64 * 64];
    __shared__ __align__(16) u16 Bsh[2][128 * 64];
    // grid is (6, M/64) = 768 blocks; flat id x-fastest; XCD = orig & 7.
    // Map so all 6 n-blocks of one m-strip are consecutive on one XCD.
    const int orig = blockIdx.y * 6 + blockIdx.x;
    const int xcd = orig & 7, i = orig >> 3;      // i in [0,96)
    const int m0 = (xcd * 16 + i / 6) * 64;
    const int n0 = (i % 6) * 128;
    const int tid = threadIdx.x;
    const int w = tid >> 6, lane = tid & 63;
    const int l32 = lane & 31, half = lane >> 5;
    const int wm = (w >> 1) * 32, wn = (w & 1) * 64;

    const int srow = lane >> 3;
    const int sgrp = (lane & 7) ^ (srow & 7);
    const int xr = l32 & 7;

    f32x16 acc[2];
#pragma unroll
    for (int j = 0; j < 2; ++j)
#pragma unroll
        for (int e = 0; e < 16; ++e) acc[j][e] = 0.f;

    // 6 stage16 per wave per K-tile (2 A + 4 B)
    auto stage_ab = [&](int buf, int k0) {
#pragma unroll
        for (int it = 0; it < 2; ++it) {
            const int c = it * 4 + w;
            const int r = c * 8 + srow;
            stage16(A + (size_t)(m0 + r) * K + k0 + sgrp * 8,
                    &Ash[buf][c * 512 + lane * 8]);
        }
#pragma unroll
        for (int it = 0; it < 4; ++it) {
            const int c = it * 4 + w;
            const int r = c * 8 + srow;
            stage16(BT + (size_t)(n0 + r) * K + k0 + sgrp * 8,
                    &Bsh[buf][c * 512 + lane * 8]);
        }
    };

    const int nk = K >> 6;
    stage_ab(0, 0);

    for (int t = 0; t < nk; ++t) {
        const int cur = t & 1;
        if (t < nk - 1) {
            stage_ab(cur ^ 1, (t + 1) * 64);
            asm volatile("s_waitcnt vmcnt(6)" ::: "memory");  // cur tile landed
        } else {
            asm volatile("s_waitcnt vmcnt(0)" ::: "memory");
        }
        __builtin_amdgcn_sched_barrier(0);
        __builtin_amdgcn_s_barrier();

        bf16x8 af[4], bfr[2][4];
#pragma unroll
        for (int kc = 0; kc < 4; ++kc)
            af[kc] = *(const bf16x8*)&Ash[cur][(wm + l32) * 64 +
                                              (((kc << 1) + half) ^ xr) * 8];
#pragma unroll
        for (int nt = 0; nt < 2; ++nt)
#pragma unroll
            for (int kc = 0; kc < 4; ++kc)
                bfr[nt][kc] = *(const bf16x8*)&Bsh[cur][(wn + nt * 32 + l32) * 64 +
                                                       (((kc << 1) + half) ^ xr) * 8];
        __builtin_amdgcn_s_setprio(1);
#pragma unroll
        for (int nt = 0; nt < 2; ++nt)
#pragma unroll
            for (int kc = 0; kc < 4; ++kc)
                acc[nt] = __builtin_amdgcn_mfma_f32_32x32x16_bf16(
                    af[kc], bfr[nt][kc], acc[nt], 0, 0, 0);
        __builtin_amdgcn_s_setprio(0);
        __builtin_amdgcn_s_barrier();
    }

#pragma unroll
    for (int nt = 0; nt < 2; ++nt) {
        const int col = n0 + wn + nt * 32 + l32;
        const float bv = bias[col];
#pragma unroll
        for (int reg = 0; reg < 16; ++reg) {
            const int row = m0 + wm + (reg & 3) + 8 * (reg >> 2) + 4 * half;
            const size_t idx = (size_t)row * N + col;
            const float rv = RESF32 ? ((const float*)resid)[idx]
                                    : b2f(((const u16*)resid)[idx]);
            outp[idx] = f2b(acc[nt][reg] + bv + rv);
        }
    }
}

// ---------- fused flash attention v7: per-nt register-lean schedule ----------
__global__ __launch_bounds__(256, 3)
void attn_fused(const u16* __restrict__ qkv, const u16* __restrict__ vt,
                u16* __restrict__ ctx) {
    __shared__ __align__(16) u16 Ksh[2][64 * 64];   // [tok][d]
    __shared__ __align__(16) u16 Vsh[2][64 * 64];   // [d][tok]

    // bijective XCD swizzle: all 16 q-tiles of one (b,h) on one XCD's L2
    const int orig = blockIdx.x;                  // 0..767
    const int swz = (orig & 7) * 96 + (orig >> 3);
    const int q0 = (swz & 15) * 128;
    const int bh = swz >> 4;                      // 0..47
    const int h = bh % 12, b = bh / 12;

    const int tid = threadIdx.x;
    const int w = tid >> 6, lane = tid & 63;
    const int l32 = lane & 31, hi5 = lane >> 5;
    const int xr8 = l32 & 7;                      // read-side swizzle key (= row&7)

    const int srow = lane >> 3;
    const int sgrp = (lane & 7) ^ (srow & 7);

    const u16* Qp = qkv + (size_t)b * 2048 * 2304 + h * 64;
    const u16* Kp = Qp + 768;
    const u16* Vtp = vt + ((size_t)(b * 12 + h) << 6) * 2048;

    // Q as B-operand (32x32x16): lane holds col q=l32, k-elems d = ks*16+hi5*8..+7
    bf16x8 qf[4];
#pragma unroll
    for (int ks = 0; ks < 4; ++ks)
        qf[ks] = *(const bf16x8*)(Qp +
            (size_t)(q0 + w * 32 + l32) * 2304 + ks * 16 + hi5 * 8);
    // drain Q loads so manual vmcnt bookkeeping below is exact
    asm volatile("s_waitcnt vmcnt(0)" ::: "memory");
    __builtin_amdgcn_sched_barrier(0);

    f32x16 oacc[2];
#pragma unroll
    for (int dt = 0; dt < 2; ++dt)
#pragma unroll
        for (int e = 0; e < 16; ++e) oacc[dt][e] = 0.f;
    float ls0 = 0.f, ls1 = 0.f, ls2 = 0.f, ls3 = 0.f;

    // 4 stage16 per wave per tile (2 K + 2 V)
    auto stage_kv = [&](int buf, int ktt) {
#pragma unroll
        for (int it = 0; it < 2; ++it) {
            const int c = it * 4 + w;
            const int r = c * 8 + srow;
            stage16(Kp + (size_t)(ktt + r) * 2304 + sgrp * 8,
                    &Ksh[buf][c * 512 + lane * 8]);
        }
#pragma unroll
        for (int it = 0; it < 2; ++it) {
            const int c = it * 4 + w;
            const int r = c * 8 + srow;      // r = d
            stage16(Vtp + (size_t)r * 2048 + ktt + sgrp * 8,
                    &Vsh[buf][c * 512 + lane * 8]);
        }
    };

    stage_kv(0, 0);

    for (int t = 0; t < 32; ++t) {
        const int cur = t & 1;
        if (t < 31) {
            stage_kv(cur ^ 1, (t + 1) * 64);
            asm volatile("s_waitcnt vmcnt(4)" ::: "memory");  // cur tile landed
        } else {
            asm volatile("s_waitcnt vmcnt(0)" ::: "memory");
        }
        __builtin_amdgcn_sched_barrier(0);
        __builtin_amdgcn_s_barrier();

#pragma unroll
        for (int nt = 0; nt < 2; ++nt) {
            // ---- K fragments (transient) + QK^T (swapped): S[tok][q] ----
            bf16x8 kfr[4];
#pragma unroll
            for (int ks = 0; ks < 4; ++ks)
                kfr[ks] = *(const bf16x8*)&Ksh[cur][(nt * 32 + l32) * 64 +
                                                   (((ks << 1) + hi5) ^ xr8) * 8];

            f32x16 sacc;
#pragma unroll
            for (int e = 0; e < 16; ++e) sacc[e] = 0.f;

            __builtin_amdgcn_s_setprio(1);
#pragma unroll
            for (int ks = 0; ks < 4; ++ks)
                sacc = __builtin_amdgcn_mfma_f32_32x32x16_bf16(
                    kfr[ks], qf[ks], sacc, 0, 0, 0);
            __builtin_amdgcn_s_setprio(0);

            // ---- this nt's V fragments early: latency hides under softmax ----
            bf16x8 vfr[4];   // [dt*2 + kh]
#pragma unroll
            for (int dt = 0; dt < 2; ++dt)
#pragma unroll
                for (int kh = 0; kh < 2; ++kh)
                    vfr[dt * 2 + kh] = *(const bf16x8*)&Vsh[cur][
                        (dt * 32 + l32) * 64 +
                        ((((nt << 2) + (kh << 1) + hi5) ^ xr8) * 8)];

            // ---- softmax (max-free, Q pre-scaled): exp2 + lane-local sums ----
#pragma unroll
            for (int e = 0; e < 16; ++e)
                sacc[e] = fast_exp2(sacc[e]);
            ls0 += (sacc[0] + sacc[1]) + (sacc[8] + sacc[9]);
            ls1 += (sacc[2] + sacc[3]) + (sacc[10] + sacc[11]);
            ls2 += (sacc[4] + sacc[5]) + (sacc[12] + sacc[13]);
            ls3 += (sacc[6] + sacc[7]) + (sacc[14] + sacc[15]);

            // ---- pack P (cvt_pk + permlane32_swap) and PV accumulate ----
            __builtin_amdgcn_s_setprio(1);
#pragma unroll
            for (int kh = 0; kh < 2; ++kh) {      // 16-token k-step
                const int rb = kh * 8;
                unsigned c01, c23, c45, c67;
                asm("v_cvt_pk_bf16_f32 %0, %1, %2"
                    : "=v"(c01) : "v"(sacc[rb + 0]), "v"(sacc[rb + 1]));
                asm("v_cvt_pk_bf16_f32 %0, %1, %2"
                    : "=v"(c23) : "v"(sacc[rb + 2]), "v"(sacc[rb + 3]));
                asm("v_cvt_pk_bf16_f32 %0, %1, %2"
                    : "=v"(c45) : "v"(sacc[rb + 4]), "v"(sacc[rb + 5]));
                asm("v_cvt_pk_bf16_f32 %0, %1, %2"
                    : "=v"(c67) : "v"(sacc[rb + 6]), "v"(sacc[rb + 7]));
                // lane<32 <-> lane>=32 half exchange: fills tokens hi5*8..+7 in order
                asm("v_permlane32_swap_b32 %0, %1" : "+v"(c01), "+v"(c45));
                asm("v_permlane32_swap_b32 %0, %1" : "+v"(c23), "+v"(c67));
                union { unsigned u[4]; bf16x8 v; } pf;
                pf.u[0] = c01; pf.u[1] = c23; pf.u[2] = c45; pf.u[3] = c67;
#pragma unroll
                for (int dt = 0; dt < 2; ++dt)
                    oacc[dt] = __builtin_amdgcn_mfma_f32_32x32x16_bf16(
                        pf.v, vfr[dt * 2 + kh], oacc[dt], 0, 0, 0);
            }
            __builtin_amdgcn_s_setprio(0);
        }
        __builtin_amdgcn_s_barrier();
    }

    // row sum: lane q=l32 holds half the tokens; partner (lane^32) has the rest
    float lsum = (ls0 + ls1) + (ls2 + ls3);
    lsum += __shfl_xor(lsum, 32);
    const float linv = 1.f / lsum;

    // per-output-row scale: row q_r's sum lives on lane q_r
    float scv[16];
#pragma unroll
    for (int reg = 0; reg < 16; ++reg) {
        const int q_r = (reg & 3) + 8 * (reg >> 2) + 4 * hi5;
        scv[reg] = __shfl(linv, q_r);
    }

#pragma unroll
    for (int dt = 0; dt < 2; ++dt)
#pragma unroll
        for (int reg = 0; reg < 16; ++reg) {
            const int q_r = (reg & 3) + 8 * (reg >> 2) + 4 * hi5;
            const int row = q0 + w * 32 + q_r;
            ctx[(size_t)(b * 2048 + row) * 768 + h * 64 + dt * 32 + l32] =
                f2b(oacc[dt][reg] * scv[reg]);
        }
}

// ---------- LayerNorm over H=768 (bf16 in); OUTF32 ? f32 out : bf16 out ----------
template <bool OUTF32>
__global__ __launch_bounds__(256)
void layernorm_k(const u16* __restrict__ y, const float* __restrict__ g,
                 const float* __restrict__ be, float* __restrict__ outf,
                 u16* __restrict__ outb) {
    const int row = blockIdx.x;
    const int tid = threadIdx.x;
    const u16* yr = y + (size_t)row * 768;
    float v[3], s = 0.f, s2 = 0.f;
#pragma unroll
    for (int i = 0; i < 3; ++i) {
        float x = b2f(yr[tid + i * 256]);
        v[i] = x; s += x; s2 += x * x;
    }
#pragma unroll
    for (int off = 32; off >= 1; off >>= 1) {
        s += __shfl_xor(s, off);
        s2 += __shfl_xor(s2, off);
    }
    __shared__ float red[2][4];
    const int w = tid >> 6;
    if ((tid & 63) == 0) { red[0][w] = s; red[1][w] = s2; }
    __syncthreads();
    s = red[0][0] + red[0][1] + red[0][2] + red[0][3];
    s2 = red[1][0] + red[1][1] + red[1][2] + red[1][3];
    const float mu = s * (1.f / 768.f);
    const float var = s2 * (1.f / 768.f) - mu * mu;
    const float rs = rsqrtf(var + 1e-12f);
#pragma unroll
    for (int i = 0; i < 3; ++i) {
        const int c = tid + i * 256;
        const float o = (v[i] - mu) * rs * g[c] + be[c];
        if (OUTF32) outf[(size_t)row * 768 + c] = o;
        else        outb[(size_t)row * 768 + c] = f2b(o);
    }
}

// ---------- orchestration ----------
extern "C" void kernel_launch(void* const* d_in, const int* in_sizes, int n_in,
                              void* d_out, int out_size, void* d_ws, size_t ws_size,
                              hipStream_t stream) {
    const float* x    = (const float*)d_in[0];
    const float* wqkv = (const float*)d_in[1];
    const float* bqkv = (const float*)d_in[2];
    const float* wout = (const float*)d_in[3];
    const float* bout = (const float*)d_in[4];
    const float* wff1 = (const float*)d_in[5];
    const float* bff1 = (const float*)d_in[6];
    const float* wff2 = (const float*)d_in[7];
    const float* bff2 = (const float*)d_in[8];
    const float* g1   = (const float*)d_in[9];
    const float* be1  = (const float*)d_in[10];
    const float* g2   = (const float*)d_in[11];
    const float* be2  = (const float*)d_in[12];

    char* ws = (char*)d_ws;
    constexpr size_t o_xb    = 0;
    constexpr size_t o_wqkvT = o_xb    + (size_t)8192 * 768 * 2;
    constexpr size_t o_woutT = o_wqkvT + (size_t)2304 * 768 * 2;
    constexpr size_t o_wff1T = o_woutT + (size_t)768 * 768 * 2;
    constexpr size_t o_wff2T = o_wff1T + (size_t)3072 * 768 * 2;
    constexpr size_t o_qkv   = o_wff2T + (size_t)768 * 3072 * 2;
    constexpr size_t o_ctx   = o_qkv   + (size_t)8192 * 2304 * 2;
    constexpr size_t o_y     = o_ctx   + (size_t)8192 * 768 * 2;
    constexpr size_t o_x1b   = o_y     + (size_t)8192 * 768 * 2;
    constexpr size_t o_vt    = o_x1b;   // vt dead before x1b is written
    constexpr size_t o_h     = o_qkv;   // hb reuses qkv+ctx region

    u16*   xb    = (u16*)(ws + o_xb);
    u16*   wqkvT = (u16*)(ws + o_wqkvT);
    u16*   woutT = (u16*)(ws + o_woutT);
    u16*   wff1T = (u16*)(ws + o_wff1T);
    u16*   wff2T = (u16*)(ws + o_wff2T);
    u16*   qkvb  = (u16*)(ws + o_qkv);
    u16*   ctxb  = (u16*)(ws + o_ctx);
    u16*   yb    = (u16*)(ws + o_y);
    u16*   x1b   = (u16*)(ws + o_x1b);
    u16*   hb    = (u16*)(ws + o_h);
    u16*   vt    = (u16*)(ws + o_vt);

    // fused prologue: x cast + 4 weight transposes
    prep<<<13056, 256, 0, stream>>>(x, xb, wqkv, wqkvT, wout, woutT,
                                    wff1, wff1T, wff2, wff2T);

    // qkv = x @ w_qkv + b ; q (pre-scaled), k -> qkvb bf16, v -> vt transposed
    gemm_bf16<3, 3><<<dim3(2304 / 192, 8192 / 128), 256, 0, stream>>>(
        xb, wqkvT, bqkv, qkvb, vt, 8192, 2304, 768);

    // fused attention -> ctx bf16 [8192, 768]; 768 blocks, XCD-swizzled in-kernel
    attn_fused<<<768, 256, 0, stream>>>(qkvb, vt, ctxb);

    // y = ctx @ w_out + b_out + x  -> bf16
    gemm_bf16_r64<true><<<dim3(768 / 128, 8192 / 64), 256, 0, stream>>>(
        ctxb, woutT, bout, x, yb, 8192, 768, 768);

    // x1 = LN(y) -> bf16 (vt dead after attention)
    layernorm_k<false><<<8192, 256, 0, stream>>>(yb, g1, be1, nullptr, x1b);

    // h = gelu(x1 @ w_ff1 + b_ff1) -> bf16 [8192, 3072]
    gemm_bf16<2, 2><<<dim3(3072 / 128, 8192 / 128), 256, 0, stream>>>(
        x1b, wff1T, bff1, hb, nullptr, 8192, 3072, 768);

    // y2 = h @ w_ff2 + b_ff2 + x1 -> bf16 (yb dead after LN1)
    gemm_bf16_r64<false><<<dim3(768 / 128, 8192 / 64), 256, 0, stream>>>(
        hb, wff2T, bff2, x1b, yb, 8192, 768, 3072);

    // out = LN(y2) -> f32
    layernorm_k<true><<<8192, 256, 0, stream>>>(yb, g2, be2, (float*)d_out, nullptr);
}